// Round 2
// baseline (1553.571 us; speedup 1.0000x reference)
//
#include <hip/hip_runtime.h>
#include <math.h>

#define B_ 4
#define S_ 2048
#define D_ 512
#define E_ 512
#define H_ 8
#define HD_ 64
#define ALPHA_ 1.0f
#define M_ (B_*S_)   // 8192

// ---------------------------------------------------------------------------
// Tiled fp32 GEMM: C[M,N] = A[M,K] @ W[N,K]^T + bias[N]
// BM=BN=64, BK=32, 256 threads, each thread computes 4x4.
// MODE 0: scatter columns into q/k/v [B,H,S,HD] layouts (QKV projection)
// MODE 1: write C row-major [M,N] (output projection)
// ---------------------------------------------------------------------------
template<int M, int N, int K, int MODE>
__global__ __launch_bounds__(256) void gemm_bt(const float* __restrict__ A,
                                               const float* __restrict__ W,
                                               const float* __restrict__ bias,
                                               float* __restrict__ out0,
                                               float* __restrict__ out1,
                                               float* __restrict__ out2) {
    __shared__ float As[32][68];   // [k][m], pad to 68 floats
    __shared__ float Bs[32][68];   // [k][n]

    const int t  = threadIdx.x;
    const int tx = t & 15;         // 0..15 -> n
    const int ty = t >> 4;         // 0..15 -> m
    const int m0 = blockIdx.y * 64;
    const int n0 = blockIdx.x * 64;

    float acc[4][4];
    #pragma unroll
    for (int i = 0; i < 4; ++i)
        #pragma unroll
        for (int j = 0; j < 4; ++j) acc[i][j] = 0.f;

    for (int k0 = 0; k0 < K; k0 += 32) {
        __syncthreads();
        // load A tile 64x32 and W tile 64x32 (512 float4 each; 2 per thread each)
        #pragma unroll
        for (int i = 0; i < 2; ++i) {
            const int l4 = t + i * 256;        // 0..511
            const int ml = l4 >> 3;            // row 0..63
            const int kl = (l4 & 7) << 2;      // k 0,4,..,28
            const float4 va = *(const float4*)&A[(size_t)(m0 + ml) * K + k0 + kl];
            As[kl + 0][ml] = va.x; As[kl + 1][ml] = va.y;
            As[kl + 2][ml] = va.z; As[kl + 3][ml] = va.w;
            const float4 vb = *(const float4*)&W[(size_t)(n0 + ml) * K + k0 + kl];
            Bs[kl + 0][ml] = vb.x; Bs[kl + 1][ml] = vb.y;
            Bs[kl + 2][ml] = vb.z; Bs[kl + 3][ml] = vb.w;
        }
        __syncthreads();

        #pragma unroll
        for (int kk = 0; kk < 32; ++kk) {
            const float4 a4 = *(const float4*)&As[kk][ty * 4];
            const float4 b4 = *(const float4*)&Bs[kk][tx * 4];
            const float a[4] = {a4.x, a4.y, a4.z, a4.w};
            const float b[4] = {b4.x, b4.y, b4.z, b4.w};
            #pragma unroll
            for (int i = 0; i < 4; ++i)
                #pragma unroll
                for (int j = 0; j < 4; ++j)
                    acc[i][j] = fmaf(a[i], b[j], acc[i][j]);
        }
    }

    #pragma unroll
    for (int i = 0; i < 4; ++i) {
        const int m = m0 + ty * 4 + i;
        #pragma unroll
        for (int j = 0; j < 4; ++j) {
            const int n = n0 + tx * 4 + j;
            const float val = acc[i][j] + bias[n];
            if (MODE == 0) {
                // column n of [3E]: head = n/192, u = n%192; u<64->q, <128->k, else v
                const int h = n / 192;
                const int u = n - h * 192;
                const int d = u & 63;
                const int b = m >> 11;          // m / S_
                const int s = m & 2047;         // m % S_
                float* dst = (u < 64) ? out0 : (u < 128 ? out1 : out2);
                dst[(((size_t)b * H_ + h) * S_ + s) * HD_ + d] = val;
            } else {
                out0[(size_t)m * N + n] = val;
            }
        }
    }
}

// ---------------------------------------------------------------------------
// max over tokens of ||x_row||^2 via atomicMax on uint bits (norms >= 0)
// one wave per row, 4 rows per block
// ---------------------------------------------------------------------------
__global__ __launch_bounds__(256) void xrow_norm_max(const float* __restrict__ x,
                                                     unsigned int* __restrict__ maxbits) {
    const int wid  = threadIdx.x >> 6;
    const int lane = threadIdx.x & 63;
    const int row  = blockIdx.x * 4 + wid;          // grid 2048 -> 8192 rows
    const float* xr = &x[(size_t)row * D_];
    float ss = 0.f;
    #pragma unroll
    for (int i = 0; i < D_ / 64; ++i) {
        const float v = xr[lane + i * 64];
        ss = fmaf(v, v, ss);
    }
    #pragma unroll
    for (int off = 32; off; off >>= 1) ss += __shfl_xor(ss, off);
    if (lane == 0) atomicMax(maxbits, __float_as_uint(ss));
}

// ---------------------------------------------------------------------------
// deterministic two-stage sum of q^2 : 1024 blocks x 256 threads x 16 elems
// ---------------------------------------------------------------------------
__global__ __launch_bounds__(256) void q_sumsq_partial(const float* __restrict__ Q,
                                                       float* __restrict__ part) {
    __shared__ float red[256];
    const size_t base = (size_t)blockIdx.x * 4096 + threadIdx.x;
    float ss = 0.f;
    #pragma unroll
    for (int i = 0; i < 16; ++i) {
        const float v = Q[base + (size_t)i * 256];
        ss = fmaf(v, v, ss);
    }
    red[threadIdx.x] = ss;
    __syncthreads();
    for (int s = 128; s; s >>= 1) {
        if (threadIdx.x < (unsigned)s) red[threadIdx.x] += red[threadIdx.x + s];
        __syncthreads();
    }
    if (threadIdx.x == 0) part[blockIdx.x] = red[0];
}

// ---------------------------------------------------------------------------
// per-key ||k||^2 : one wave per key row (64 elems), 4 rows/block
// ---------------------------------------------------------------------------
__global__ __launch_bounds__(256) void k_norm2_kernel(const float* __restrict__ Kk,
                                                      float* __restrict__ kn2) {
    const int wid  = threadIdx.x >> 6;
    const int lane = threadIdx.x & 63;
    const int row  = blockIdx.x * 4 + wid;          // grid 16384 -> 65536 rows
    const float v = Kk[(size_t)row * HD_ + lane];
    float ss = v * v;
    #pragma unroll
    for (int off = 32; off; off >>= 1) ss += __shfl_xor(ss, off);
    if (lane == 0) kn2[row] = ss;
}

// ---------------------------------------------------------------------------
// finalize: scale = ALPHA / (sqrt(sum q^2) * sqrt(max row norm^2))
// ---------------------------------------------------------------------------
__global__ __launch_bounds__(256) void finalize_scale(const float* __restrict__ part,
                                                      const unsigned int* __restrict__ maxbits,
                                                      float* __restrict__ scal) {
    __shared__ float red[256];
    float ss = 0.f;
    for (int i = threadIdx.x; i < 1024; i += 256) ss += part[i];
    red[threadIdx.x] = ss;
    __syncthreads();
    for (int s = 128; s; s >>= 1) {
        if (threadIdx.x < (unsigned)s) red[threadIdx.x] += red[threadIdx.x + s];
        __syncthreads();
    }
    if (threadIdx.x == 0) {
        const float fro  = sqrtf(red[0]);
        const float inf2 = sqrtf(__uint_as_float(*maxbits));
        scal[0] = ALPHA_ / (fro * inf2);
    }
}

// ---------------------------------------------------------------------------
// flash-style attention, fp32. 256 threads/block, 1 q-row per thread.
// scores s_ij = scale*(2*q.k - ||k_j||^2)  (q_norm2 row-constant dropped)
// ---------------------------------------------------------------------------
__global__ __launch_bounds__(256) void attn_kernel(const float* __restrict__ Q,
                                                   const float* __restrict__ Kk,
                                                   const float* __restrict__ V,
                                                   const float* __restrict__ KN2,
                                                   const float* __restrict__ scal,
                                                   float* __restrict__ VALS) {
    __shared__ float ks[64][68];
    __shared__ float vs[64][68];
    __shared__ float kn2s[64];

    const int t   = threadIdx.x;
    const int bh  = blockIdx.y;                 // 0..31
    const int row = blockIdx.x * 256 + t;       // q row in [0,S)
    const float scale = scal[0];

    // load q row into registers
    float qreg[64];
    {
        const float* qrow = &Q[((size_t)bh * S_ + row) * HD_];
        #pragma unroll
        for (int d4 = 0; d4 < 16; ++d4) {
            const float4 v4 = *(const float4*)&qrow[d4 * 4];
            qreg[4 * d4 + 0] = v4.x; qreg[4 * d4 + 1] = v4.y;
            qreg[4 * d4 + 2] = v4.z; qreg[4 * d4 + 3] = v4.w;
        }
    }

    float acc[64];
    #pragma unroll
    for (int d = 0; d < 64; ++d) acc[d] = 0.f;
    float m = -1e30f, l = 0.f;

    const float* kbase   = &Kk[(size_t)bh * S_ * HD_];
    const float* vbase   = &V[(size_t)bh * S_ * HD_];
    const float* kn2base = &KN2[(size_t)bh * S_];

    for (int kt = 0; kt < S_; kt += 64) {
        __syncthreads();
        // stage K and V tiles (64x64 each = 1024 float4 each; 4/thread each)
        #pragma unroll
        for (int i = 0; i < 4; ++i) {
            const int l4 = t + i * 256;         // 0..1023
            const int r  = l4 >> 4;             // 0..63
            const int c4 = l4 & 15;
            *(float4*)&ks[r][c4 * 4] = *(const float4*)&kbase[(size_t)(kt + r) * HD_ + c4 * 4];
            *(float4*)&vs[r][c4 * 4] = *(const float4*)&vbase[(size_t)(kt + r) * HD_ + c4 * 4];
        }
        if (t < 64) kn2s[t] = kn2base[kt + t];
        __syncthreads();

        for (int j = 0; j < 64; ++j) {
            float d0 = 0.f, d1 = 0.f, d2 = 0.f, d3 = 0.f;
            #pragma unroll
            for (int d4 = 0; d4 < 16; ++d4) {
                const float4 k4 = *(const float4*)&ks[j][d4 * 4];
                d0 = fmaf(qreg[4 * d4 + 0], k4.x, d0);
                d1 = fmaf(qreg[4 * d4 + 1], k4.y, d1);
                d2 = fmaf(qreg[4 * d4 + 2], k4.z, d2);
                d3 = fmaf(qreg[4 * d4 + 3], k4.w, d3);
            }
            const float dot = (d0 + d1) + (d2 + d3);
            const float s = scale * (2.f * dot - kn2s[j]);
            float p;
            if (s > m) {                         // new running max (rare): rescale
                const float corr = __expf(m - s);
                m = s;
                l = fmaf(l, corr, 1.0f);
                #pragma unroll
                for (int d = 0; d < 64; ++d) acc[d] *= corr;
                p = 1.0f;
            } else {
                p = __expf(s - m);
                l += p;
            }
            #pragma unroll
            for (int d4 = 0; d4 < 16; ++d4) {
                const float4 v4 = *(const float4*)&vs[j][d4 * 4];
                acc[4 * d4 + 0] = fmaf(p, v4.x, acc[4 * d4 + 0]);
                acc[4 * d4 + 1] = fmaf(p, v4.y, acc[4 * d4 + 1]);
                acc[4 * d4 + 2] = fmaf(p, v4.z, acc[4 * d4 + 2]);
                acc[4 * d4 + 3] = fmaf(p, v4.w, acc[4 * d4 + 3]);
            }
        }
    }

    // write values in [B,S,E] layout (E index = h*HD + d)
    const float inv = 1.0f / l;
    const int b = bh / H_, h = bh % H_;
    float* dst = &VALS[((size_t)b * S_ + row) * E_ + h * HD_];
    #pragma unroll
    for (int d4 = 0; d4 < 16; ++d4) {
        float4 o;
        o.x = acc[4 * d4 + 0] * inv; o.y = acc[4 * d4 + 1] * inv;
        o.z = acc[4 * d4 + 2] * inv; o.w = acc[4 * d4 + 3] * inv;
        *(float4*)&dst[d4 * 4] = o;
    }
}

// ---------------------------------------------------------------------------
extern "C" void kernel_launch(void* const* d_in, const int* in_sizes, int n_in,
                              void* d_out, int out_size, void* d_ws, size_t ws_size,
                              hipStream_t stream) {
    const float* x    = (const float*)d_in[0];
    const float* Wqkv = (const float*)d_in[1];
    const float* bqkv = (const float*)d_in[2];
    const float* Wo   = (const float*)d_in[3];
    const float* bo   = (const float*)d_in[4];
    float* out = (float*)d_out;

    char* ws = (char*)d_ws;
    float* Qw   = (float*)(ws);                              // 16 MB
    float* Kw   = (float*)(ws + ((size_t)16 << 20));         // 16 MB
    float* Vw   = (float*)(ws + ((size_t)32 << 20));         // 16 MB
    float* VAL  = (float*)(ws + ((size_t)48 << 20));         // 16 MB
    float* KN2  = (float*)(ws + ((size_t)64 << 20));         // 256 KB
    float* PART = (float*)(ws + ((size_t)64 << 20) + (256 << 10));  // 4 KB
    float* SCAL = (float*)(ws + ((size_t)64 << 20) + (260 << 10));
    unsigned int* MAXB = (unsigned int*)(SCAL + 1);

    hipMemsetAsync(MAXB, 0, sizeof(unsigned int), stream);

    // 1) QKV projection, scattered into [B,H,S,HD] q/k/v
    gemm_bt<M_, 3 * E_, D_, 0><<<dim3(24, 128), 256, 0, stream>>>(x, Wqkv, bqkv, Qw, Kw, Vw);

    // 2) normalizer scalars + key norms
    xrow_norm_max<<<2048, 256, 0, stream>>>(x, MAXB);
    q_sumsq_partial<<<1024, 256, 0, stream>>>(Qw, PART);
    k_norm2_kernel<<<16384, 256, 0, stream>>>(Kw, KN2);
    finalize_scale<<<1, 256, 0, stream>>>(PART, MAXB, SCAL);

    // 3) attention -> values [B,S,E]
    attn_kernel<<<dim3(S_ / 256, B_ * H_), 256, 0, stream>>>(Qw, Kw, Vw, KN2, SCAL, VAL);

    // 4) output projection
    gemm_bt<M_, E_, E_, 1><<<dim3(8, 128), 256, 0, stream>>>(VAL, Wo, bo, out, nullptr, nullptr);
}

// Round 5
// 476.746 us; speedup vs baseline: 3.2587x; 3.2587x over previous
//
#include <hip/hip_runtime.h>
#include <math.h>

#define B_ 4
#define S_ 2048
#define D_ 512
#define E_ 512
#define H_ 8
#define HD_ 64
#define ALPHA_ 1.0f
#define M_ (B_*S_)   // 8192

typedef __attribute__((ext_vector_type(8))) short bf16x8;
typedef __attribute__((ext_vector_type(4))) float f32x4;

__device__ inline float bf2f(unsigned short u) {
    return __uint_as_float(((unsigned)u) << 16);
}
__device__ inline unsigned short f2bf(float f) {
    unsigned u = __float_as_uint(f);
    u = (u + 0x7FFF + ((u >> 16) & 1)) >> 16;   // RNE
    return (unsigned short)u;
}
__device__ inline unsigned pack2bf(float a, float b) {
    return (unsigned)f2bf(a) | ((unsigned)f2bf(b) << 16);
}

// ---------------------------------------------------------------------------
// Tiled fp32 GEMM: C[M,N] = A[M,K] @ W[N,K]^T + bias[N]
// MODE 0: scatter bf16 into Q [bh][S][64], K [bh][S][64], V^T [bh][64][S]
// MODE 1: write fp32 C row-major [M,N] (output projection)
// ---------------------------------------------------------------------------
template<int M, int N, int K, int MODE>
__global__ __launch_bounds__(256) void gemm_bt(const float* __restrict__ A,
                                               const float* __restrict__ W,
                                               const float* __restrict__ bias,
                                               void* __restrict__ out0,
                                               void* __restrict__ out1,
                                               void* __restrict__ out2) {
    __shared__ float As[32][68];
    __shared__ float Bs[32][68];

    const int t  = threadIdx.x;
    const int tx = t & 15;
    const int ty = t >> 4;
    const int m0 = blockIdx.y * 64;
    const int n0 = blockIdx.x * 64;

    float acc[4][4];
    #pragma unroll
    for (int i = 0; i < 4; ++i)
        #pragma unroll
        for (int j = 0; j < 4; ++j) acc[i][j] = 0.f;

    for (int k0 = 0; k0 < K; k0 += 32) {
        __syncthreads();
        #pragma unroll
        for (int i = 0; i < 2; ++i) {
            const int l4 = t + i * 256;
            const int ml = l4 >> 3;
            const int kl = (l4 & 7) << 2;
            const float4 va = *(const float4*)&A[(size_t)(m0 + ml) * K + k0 + kl];
            As[kl + 0][ml] = va.x; As[kl + 1][ml] = va.y;
            As[kl + 2][ml] = va.z; As[kl + 3][ml] = va.w;
            const float4 vb = *(const float4*)&W[(size_t)(n0 + ml) * K + k0 + kl];
            Bs[kl + 0][ml] = vb.x; Bs[kl + 1][ml] = vb.y;
            Bs[kl + 2][ml] = vb.z; Bs[kl + 3][ml] = vb.w;
        }
        __syncthreads();

        #pragma unroll
        for (int kk = 0; kk < 32; ++kk) {
            const float4 a4 = *(const float4*)&As[kk][ty * 4];
            const float4 b4 = *(const float4*)&Bs[kk][tx * 4];
            const float a[4] = {a4.x, a4.y, a4.z, a4.w};
            const float b[4] = {b4.x, b4.y, b4.z, b4.w};
            #pragma unroll
            for (int i = 0; i < 4; ++i)
                #pragma unroll
                for (int j = 0; j < 4; ++j)
                    acc[i][j] = fmaf(a[i], b[j], acc[i][j]);
        }
    }

    #pragma unroll
    for (int i = 0; i < 4; ++i) {
        const int m = m0 + ty * 4 + i;
        #pragma unroll
        for (int j = 0; j < 4; ++j) {
            const int n = n0 + tx * 4 + j;
            const float val = acc[i][j] + bias[n];
            if (MODE == 0) {
                const int h = n / 192;
                const int u = n - h * 192;
                const int d = u & 63;
                const int b = m >> 11;
                const int s = m & 2047;
                const unsigned short bv = f2bf(val);
                if (u < 64)
                    ((unsigned short*)out0)[(((size_t)b * H_ + h) * S_ + s) * HD_ + d] = bv;
                else if (u < 128)
                    ((unsigned short*)out1)[(((size_t)b * H_ + h) * S_ + s) * HD_ + d] = bv;
                else
                    ((unsigned short*)out2)[(((size_t)b * H_ + h) * HD_ + d) * S_ + s] = bv;
            } else {
                ((float*)out0)[(size_t)m * N + n] = val;
            }
        }
    }
}

// ---------------------------------------------------------------------------
// max over tokens of ||x_row||^2 (fp32 x) via atomicMax on uint bits
// ---------------------------------------------------------------------------
__global__ __launch_bounds__(256) void xrow_norm_max(const float* __restrict__ x,
                                                     unsigned int* __restrict__ maxbits) {
    const int wid  = threadIdx.x >> 6;
    const int lane = threadIdx.x & 63;
    const int row  = blockIdx.x * 4 + wid;
    const float* xr = &x[(size_t)row * D_];
    float ss = 0.f;
    #pragma unroll
    for (int i = 0; i < D_ / 64; ++i) {
        const float v = xr[lane + i * 64];
        ss = fmaf(v, v, ss);
    }
    #pragma unroll
    for (int off = 32; off; off >>= 1) ss += __shfl_xor(ss, off);
    if (lane == 0) atomicMax(maxbits, __float_as_uint(ss));
}

// ---------------------------------------------------------------------------
// deterministic two-stage sum of q^2 over bf16 Q (4M elements)
// 1024 blocks x 256 threads x 16 elems (2 x uint4 = 2 x 8 bf16)
// ---------------------------------------------------------------------------
__global__ __launch_bounds__(256) void q_sumsq_partial(const unsigned short* __restrict__ Q,
                                                       float* __restrict__ part) {
    __shared__ float red[256];
    float ss = 0.f;
    #pragma unroll
    for (int i = 0; i < 2; ++i) {
        const size_t e0 = ((size_t)blockIdx.x * 512 + i * 256 + threadIdx.x) * 8;
        const uint4 v = *(const uint4*)&Q[e0];
        const unsigned w[4] = {v.x, v.y, v.z, v.w};
        #pragma unroll
        for (int j = 0; j < 4; ++j) {
            const float lo = __uint_as_float(w[j] << 16);
            const float hi = __uint_as_float(w[j] & 0xFFFF0000u);
            ss = fmaf(lo, lo, ss);
            ss = fmaf(hi, hi, ss);
        }
    }
    red[threadIdx.x] = ss;
    __syncthreads();
    for (int s = 128; s; s >>= 1) {
        if (threadIdx.x < (unsigned)s) red[threadIdx.x] += red[threadIdx.x + s];
        __syncthreads();
    }
    if (threadIdx.x == 0) part[blockIdx.x] = red[0];
}

// ---------------------------------------------------------------------------
// per-key ||k||^2 from bf16 K: one wave per key row
// ---------------------------------------------------------------------------
__global__ __launch_bounds__(256) void k_norm2_kernel(const unsigned short* __restrict__ Kk,
                                                      float* __restrict__ kn2) {
    const int wid  = threadIdx.x >> 6;
    const int lane = threadIdx.x & 63;
    const int row  = blockIdx.x * 4 + wid;
    const float v = bf2f(Kk[(size_t)row * HD_ + lane]);
    float ss = v * v;
    #pragma unroll
    for (int off = 32; off; off >>= 1) ss += __shfl_xor(ss, off);
    if (lane == 0) kn2[row] = ss;
}

// ---------------------------------------------------------------------------
__global__ __launch_bounds__(256) void finalize_scale(const float* __restrict__ part,
                                                      const unsigned int* __restrict__ maxbits,
                                                      float* __restrict__ scal) {
    __shared__ float red[256];
    float ss = 0.f;
    for (int i = threadIdx.x; i < 1024; i += 256) ss += part[i];
    red[threadIdx.x] = ss;
    __syncthreads();
    for (int s = 128; s; s >>= 1) {
        if (threadIdx.x < (unsigned)s) red[threadIdx.x] += red[threadIdx.x + s];
        __syncthreads();
    }
    if (threadIdx.x == 0) {
        const float fro  = sqrtf(red[0]);
        const float inf2 = sqrtf(__uint_as_float(*maxbits));
        scal[0] = ALPHA_ / (fro * inf2);
    }
}

// ---------------------------------------------------------------------------
// bf16 MFMA flash attention. 256 thr = 4 waves; 64 q-rows/block; KV tiles 64.
// Swapped QK^T: S^T = mfma(K, Q) so softmax col = q (2 shuffles/reduce).
// P -> bf16 -> swizzled LDS -> A-operand of PV. V staged pre-transposed.
// All LDS tiles XOR-swizzled: byte ^= (row&7)<<4  (G4: kills 16-way conflicts).
// ---------------------------------------------------------------------------
__global__ __launch_bounds__(256) void attn_mfma(const unsigned short* __restrict__ Qb,
                                                 const unsigned short* __restrict__ Kb,
                                                 const unsigned short* __restrict__ Vtb,
                                                 const float* __restrict__ KN2,
                                                 const float* __restrict__ scal,
                                                 float* __restrict__ VALS) {
    __shared__ __align__(16) char lds[3 * 8192 + 256];
    char* Kt = lds;                  // [64 k][64 d] bf16, swizzled
    char* Vt = lds + 8192;           // [64 d][64 k] bf16, swizzled
    char* Pl = lds + 16384;          // 4 waves x [16 q][64 k] bf16, swizzled
    float* kn2s = (float*)(lds + 24576);

    const int t  = threadIdx.x;
    const int w  = t >> 6;
    const int l  = t & 63;
    const int g  = l >> 4;           // 0..3
    const int c  = l & 15;           // 0..15
    const int bh = blockIdx.y;       // b*H + h
    const int qb = blockIdx.x;       // q-block of 64
    const float scale = scal[0];

    // Q fragments for this wave's 16 q-rows (held in registers)
    const int qrow = qb * 64 + w * 16 + c;
    const size_t qoff = ((size_t)bh * S_ + qrow) * HD_;
    const bf16x8 qf0 = *(const bf16x8*)&Qb[qoff + g * 8];
    const bf16x8 qf1 = *(const bf16x8*)&Qb[qoff + 32 + g * 8];

    f32x4 acc[4];
    #pragma unroll
    for (int dt = 0; dt < 4; ++dt)
        #pragma unroll
        for (int r = 0; r < 4; ++r) acc[dt][r] = 0.f;
    float mrun = -1e30f, lrun = 0.f;

    const size_t kbase  = (size_t)bh * S_ * HD_;
    const size_t vtbase = (size_t)bh * HD_ * S_;
    char* Pw = Pl + w * 2048;
    const int swc = (c & 7) << 4;

    for (int kt0 = 0; kt0 < S_; kt0 += 64) {
        __syncthreads();
        // stage K [64][64] and V^T [64][64], both swizzled
        #pragma unroll
        for (int i = 0; i < 2; ++i) {
            const int idx = t + i * 256;         // 0..511
            const int r   = idx >> 3;            // 0..63
            const int cb  = (idx & 7) * 16;      // byte col 0..112
            const int dst = r * 128 + (cb ^ ((r & 7) << 4));
            *(uint4*)(Kt + dst) = *(const uint4*)&Kb[kbase + (size_t)(kt0 + r) * HD_ + (cb >> 1)];
            *(uint4*)(Vt + dst) = *(const uint4*)&Vtb[vtbase + (size_t)r * S_ + kt0 + (cb >> 1)];
        }
        if (t < 64) kn2s[t] = KN2[(size_t)bh * S_ + kt0 + t];
        __syncthreads();

        // S^T[k][q] = K . Q^T  (4 k-subtiles x 2 k-dim chunks)
        float sl[16];
        #pragma unroll
        for (int kt = 0; kt < 4; ++kt) {
            const int r  = kt * 16 + c;
            const int sw = (r & 7) << 4;
            const bf16x8 ka0 = *(const bf16x8*)(Kt + r * 128 + ((g * 16) ^ sw));
            const bf16x8 ka1 = *(const bf16x8*)(Kt + r * 128 + ((64 + g * 16) ^ sw));
            f32x4 sacc = {0.f, 0.f, 0.f, 0.f};
            sacc = __builtin_amdgcn_mfma_f32_16x16x32_bf16(ka0, qf0, sacc, 0, 0, 0);
            sacc = __builtin_amdgcn_mfma_f32_16x16x32_bf16(ka1, qf1, sacc, 0, 0, 0);
            #pragma unroll
            for (int rg = 0; rg < 4; ++rg)
                sl[kt * 4 + rg] = scale * (2.f * sacc[rg] - kn2s[kt * 16 + g * 4 + rg]);
        }

        // online softmax for q = c (column of S^T); row-reduce = 2 shuffles
        float pmax = sl[0];
        #pragma unroll
        for (int j = 1; j < 16; ++j) pmax = fmaxf(pmax, sl[j]);
        pmax = fmaxf(pmax, __shfl_xor(pmax, 16));
        pmax = fmaxf(pmax, __shfl_xor(pmax, 32));
        const float mnew = fmaxf(mrun, pmax);
        const float corr = __expf(mrun - mnew);
        lrun *= corr;
        #pragma unroll
        for (int dt = 0; dt < 4; ++dt)
            #pragma unroll
            for (int r = 0; r < 4; ++r) acc[dt][r] *= corr;
        float p[16];
        float psum = 0.f;
        #pragma unroll
        for (int j = 0; j < 16; ++j) { p[j] = __expf(sl[j] - mnew); psum += p[j]; }
        psum += __shfl_xor(psum, 16);
        psum += __shfl_xor(psum, 32);
        lrun += psum;
        mrun = mnew;

        // pack P -> bf16 -> wave-private swizzled LDS [16 q][64 k]
        #pragma unroll
        for (int kt = 0; kt < 4; ++kt) {
            const int cb = kt * 32 + g * 8;
            *(unsigned*)(Pw + c * 128 + (cb ^ swc))       = pack2bf(p[kt * 4 + 0], p[kt * 4 + 1]);
            *(unsigned*)(Pw + c * 128 + ((cb + 4) ^ swc)) = pack2bf(p[kt * 4 + 2], p[kt * 4 + 3]);
        }
        asm volatile("s_waitcnt lgkmcnt(0)" ::: "memory");
        __builtin_amdgcn_sched_barrier(0);

        // PV: O[q][d] += P[q][k] V[k][d]
        const bf16x8 pa0 = *(const bf16x8*)(Pw + c * 128 + ((g * 16) ^ swc));
        const bf16x8 pa1 = *(const bf16x8*)(Pw + c * 128 + ((64 + g * 16) ^ swc));
        #pragma unroll
        for (int dt = 0; dt < 4; ++dt) {
            const int r  = dt * 16 + c;
            const int sw = (r & 7) << 4;       // == swc
            const bf16x8 vb0 = *(const bf16x8*)(Vt + r * 128 + ((g * 16) ^ sw));
            const bf16x8 vb1 = *(const bf16x8*)(Vt + r * 128 + ((64 + g * 16) ^ sw));
            acc[dt] = __builtin_amdgcn_mfma_f32_16x16x32_bf16(pa0, vb0, acc[dt], 0, 0, 0);
            acc[dt] = __builtin_amdgcn_mfma_f32_16x16x32_bf16(pa1, vb1, acc[dt], 0, 0, 0);
        }
    }

    // epilogue: lane holds O[q = g*4+reg][d = dt*16+c]; l lives at col c -> shfl
    const int b = bh >> 3, h = bh & 7;
    #pragma unroll
    for (int reg = 0; reg < 4; ++reg) {
        const float lq  = __shfl(lrun, g * 4 + reg);
        const float inv = 1.0f / lq;
        const int qg = qb * 64 + w * 16 + g * 4 + reg;
        float* dst = &VALS[((size_t)b * S_ + qg) * E_ + h * HD_];
        #pragma unroll
        for (int dt = 0; dt < 4; ++dt)
            dst[dt * 16 + c] = acc[dt][reg] * inv;
    }
}

// ---------------------------------------------------------------------------
extern "C" void kernel_launch(void* const* d_in, const int* in_sizes, int n_in,
                              void* d_out, int out_size, void* d_ws, size_t ws_size,
                              hipStream_t stream) {
    const float* x    = (const float*)d_in[0];
    const float* Wqkv = (const float*)d_in[1];
    const float* bqkv = (const float*)d_in[2];
    const float* Wo   = (const float*)d_in[3];
    const float* bo   = (const float*)d_in[4];
    float* out = (float*)d_out;

    char* ws = (char*)d_ws;
    unsigned short* Qb  = (unsigned short*)(ws);                       // 8 MB
    unsigned short* Kb  = (unsigned short*)(ws + ((size_t)8  << 20));  // 8 MB
    unsigned short* Vtb = (unsigned short*)(ws + ((size_t)16 << 20));  // 8 MB
    float* VAL  = (float*)(ws + ((size_t)24 << 20));                   // 16 MB
    float* KN2  = (float*)(ws + ((size_t)40 << 20));                   // 256 KB
    float* PART = (float*)(ws + ((size_t)40 << 20) + (256 << 10));     // 4 KB
    float* SCAL = (float*)(ws + ((size_t)40 << 20) + (260 << 10));
    unsigned int* MAXB = (unsigned int*)(SCAL + 1);

    hipMemsetAsync(MAXB, 0, sizeof(unsigned int), stream);

    // 1) QKV projection -> bf16 Q,K [bh][S][64] and V^T [bh][64][S]
    gemm_bt<M_, 3 * E_, D_, 0><<<dim3(24, 128), 256, 0, stream>>>(x, Wqkv, bqkv, Qb, Kb, Vtb);

    // 2) normalizer scalars + key norms
    xrow_norm_max<<<2048, 256, 0, stream>>>(x, MAXB);
    q_sumsq_partial<<<1024, 256, 0, stream>>>(Qb, PART);
    k_norm2_kernel<<<16384, 256, 0, stream>>>(Kb, KN2);
    finalize_scale<<<1, 256, 0, stream>>>(PART, MAXB, SCAL);

    // 3) MFMA flash attention -> VAL [B,S,E] fp32
    attn_mfma<<<dim3(S_ / 64, B_ * H_), 256, 0, stream>>>(Qb, Kb, Vtb, KN2, SCAL, VAL);

    // 4) output projection (fp32)
    gemm_bt<M_, E_, E_, 1><<<dim3(8, 128), 256, 0, stream>>>(VAL, Wo, bo, out, nullptr, nullptr);
}

// Round 6
// 277.271 us; speedup vs baseline: 5.6031x; 1.7194x over previous
//
#include <hip/hip_runtime.h>
#include <math.h>

#define B_ 4
#define S_ 2048
#define D_ 512
#define E_ 512
#define H_ 8
#define HD_ 64
#define ALPHA_ 1.0f
#define M_ (B_*S_)   // 8192

typedef __attribute__((ext_vector_type(8))) short bf16x8;
typedef __attribute__((ext_vector_type(4))) float f32x4;

__device__ inline float bf2f(unsigned short u) {
    return __uint_as_float(((unsigned)u) << 16);
}
__device__ inline unsigned short f2bf(float f) {
    unsigned u = __float_as_uint(f);
    u = (u + 0x7FFF + ((u >> 16) & 1)) >> 16;   // RNE
    return (unsigned short)u;
}
__device__ inline unsigned pack2bf(float a, float b) {
    return (unsigned)f2bf(a) | ((unsigned)f2bf(b) << 16);
}

// ---------------------------------------------------------------------------
// fp32 -> bf16 conversion, 8 elems/thread (2 float4 in, 1 uint4 out)
// ---------------------------------------------------------------------------
__global__ __launch_bounds__(256) void cvt_bf16(const float* __restrict__ in,
                                                unsigned short* __restrict__ out,
                                                int n8) {
    const int i = blockIdx.x * 256 + threadIdx.x;
    if (i >= n8) return;
    const float4 a = *(const float4*)&in[(size_t)i * 8];
    const float4 b = *(const float4*)&in[(size_t)i * 8 + 4];
    uint4 o;
    o.x = pack2bf(a.x, a.y); o.y = pack2bf(a.z, a.w);
    o.z = pack2bf(b.x, b.y); o.w = pack2bf(b.z, b.w);
    *(uint4*)&out[(size_t)i * 8] = o;
}

// ---------------------------------------------------------------------------
// bf16 MFMA GEMM: C[M,N] = A[M,512] @ W[N,512]^T + bias[N]
// 128x128 tile, BK=64, 256 thr = 4 waves (2x2), each wave 64x64 (4x4 frags).
// LDS tiles [128][64] bf16, XOR-swizzled (byte ^= (row&7)<<4).
// MODE 0: scatter bf16 -> Q [bh][S][64], K [bh][S][64], V^T [bh][64][S]
// MODE 1: fp32 C row-major [M][N]
// ---------------------------------------------------------------------------
template<int N, int MODE>
__global__ __launch_bounds__(256) void gemm_mfma(const unsigned short* __restrict__ Abf,
                                                 const unsigned short* __restrict__ Wbf,
                                                 const float* __restrict__ bias,
                                                 void* __restrict__ out0,
                                                 void* __restrict__ out1,
                                                 void* __restrict__ out2) {
    __shared__ __align__(16) char At[16384];
    __shared__ __align__(16) char Wt[16384];

    const int t  = threadIdx.x;
    const int w  = t >> 6;
    const int l  = t & 63;
    const int g  = l >> 4;            // 0..3
    const int c  = l & 15;            // 0..15
    const int wm = w >> 1;            // 0..1
    const int wn = w & 1;             // 0..1
    const int m0 = blockIdx.y * 128;
    const int n0 = blockIdx.x * 128;

    f32x4 acc[4][4];
    #pragma unroll
    for (int i = 0; i < 4; ++i)
        #pragma unroll
        for (int j = 0; j < 4; ++j)
            #pragma unroll
            for (int r = 0; r < 4; ++r) acc[i][j][r] = 0.f;

    for (int k0 = 0; k0 < 512; k0 += 64) {
        __syncthreads();
        // stage A[128][64] and W[128][64] (1024 uint4 each; 4/thread each)
        #pragma unroll
        for (int i = 0; i < 4; ++i) {
            const int idx = t + i * 256;          // 0..1023
            const int r   = idx >> 3;             // 0..127
            const int j   = idx & 7;              // 0..7
            const int dst = r * 128 + ((j * 16) ^ ((r & 7) << 4));
            *(uint4*)(At + dst) = *(const uint4*)&Abf[(size_t)(m0 + r) * 512 + k0 + j * 8];
            *(uint4*)(Wt + dst) = *(const uint4*)&Wbf[(size_t)(n0 + r) * 512 + k0 + j * 8];
        }
        __syncthreads();

        // fragments: A rows (m), W rows (n); i-index = c, k-chunk kc (2x32)
        bf16x8 af[4][2], wf[4][2];
        #pragma unroll
        for (int mt = 0; mt < 4; ++mt) {
            const int row = wm * 64 + mt * 16 + c;
            const int sw  = (row & 7) << 4;
            #pragma unroll
            for (int kc = 0; kc < 2; ++kc)
                af[mt][kc] = *(const bf16x8*)(At + row * 128 + (((kc * 4 + g) * 16) ^ sw));
        }
        #pragma unroll
        for (int nt = 0; nt < 4; ++nt) {
            const int row = wn * 64 + nt * 16 + c;
            const int sw  = (row & 7) << 4;
            #pragma unroll
            for (int kc = 0; kc < 2; ++kc)
                wf[nt][kc] = *(const bf16x8*)(Wt + row * 128 + (((kc * 4 + g) * 16) ^ sw));
        }
        #pragma unroll
        for (int mt = 0; mt < 4; ++mt)
            #pragma unroll
            for (int nt = 0; nt < 4; ++nt) {
                acc[mt][nt] = __builtin_amdgcn_mfma_f32_16x16x32_bf16(af[mt][0], wf[nt][0], acc[mt][nt], 0, 0, 0);
                acc[mt][nt] = __builtin_amdgcn_mfma_f32_16x16x32_bf16(af[mt][1], wf[nt][1], acc[mt][nt], 0, 0, 0);
            }
    }

    // epilogue: m = m0+wm*64+mt*16+g*4+reg, n = n0+wn*64+nt*16+c
    #pragma unroll
    for (int mt = 0; mt < 4; ++mt) {
        #pragma unroll
        for (int reg = 0; reg < 4; ++reg) {
            const int m = m0 + wm * 64 + mt * 16 + g * 4 + reg;
            #pragma unroll
            for (int nt = 0; nt < 4; ++nt) {
                const int n = n0 + wn * 64 + nt * 16 + c;
                const float val = acc[mt][nt][reg] + bias[n];
                if (MODE == 0) {
                    const int h = n / 192;
                    const int u = n - h * 192;
                    const int d = u & 63;
                    const int b = m >> 11;
                    const int s = m & 2047;
                    const unsigned short bv = f2bf(val);
                    if (u < 64)
                        ((unsigned short*)out0)[(((size_t)b * H_ + h) * S_ + s) * HD_ + d] = bv;
                    else if (u < 128)
                        ((unsigned short*)out1)[(((size_t)b * H_ + h) * S_ + s) * HD_ + d] = bv;
                    else
                        ((unsigned short*)out2)[(((size_t)b * H_ + h) * HD_ + d) * S_ + s] = bv;
                } else {
                    ((float*)out0)[(size_t)m * N + n] = val;
                }
            }
        }
    }
}

// ---------------------------------------------------------------------------
// max over tokens of ||x_row||^2 (fp32 x) via atomicMax on uint bits
// ---------------------------------------------------------------------------
__global__ __launch_bounds__(256) void xrow_norm_max(const float* __restrict__ x,
                                                     unsigned int* __restrict__ maxbits) {
    const int wid  = threadIdx.x >> 6;
    const int lane = threadIdx.x & 63;
    const int row  = blockIdx.x * 4 + wid;
    const float* xr = &x[(size_t)row * D_];
    float ss = 0.f;
    #pragma unroll
    for (int i = 0; i < D_ / 64; ++i) {
        const float v = xr[lane + i * 64];
        ss = fmaf(v, v, ss);
    }
    #pragma unroll
    for (int off = 32; off; off >>= 1) ss += __shfl_xor(ss, off);
    if (lane == 0) atomicMax(maxbits, __float_as_uint(ss));
}

// ---------------------------------------------------------------------------
// deterministic two-stage sum of q^2 over bf16 Q (4M elements)
// ---------------------------------------------------------------------------
__global__ __launch_bounds__(256) void q_sumsq_partial(const unsigned short* __restrict__ Q,
                                                       float* __restrict__ part) {
    __shared__ float red[256];
    float ss = 0.f;
    #pragma unroll
    for (int i = 0; i < 2; ++i) {
        const size_t e0 = ((size_t)blockIdx.x * 512 + i * 256 + threadIdx.x) * 8;
        const uint4 v = *(const uint4*)&Q[e0];
        const unsigned w[4] = {v.x, v.y, v.z, v.w};
        #pragma unroll
        for (int j = 0; j < 4; ++j) {
            const float lo = __uint_as_float(w[j] << 16);
            const float hi = __uint_as_float(w[j] & 0xFFFF0000u);
            ss = fmaf(lo, lo, ss);
            ss = fmaf(hi, hi, ss);
        }
    }
    red[threadIdx.x] = ss;
    __syncthreads();
    for (int s = 128; s; s >>= 1) {
        if (threadIdx.x < (unsigned)s) red[threadIdx.x] += red[threadIdx.x + s];
        __syncthreads();
    }
    if (threadIdx.x == 0) part[blockIdx.x] = red[0];
}

// ---------------------------------------------------------------------------
// per-key ||k||^2 from bf16 K: one wave per key row
// ---------------------------------------------------------------------------
__global__ __launch_bounds__(256) void k_norm2_kernel(const unsigned short* __restrict__ Kk,
                                                      float* __restrict__ kn2) {
    const int wid  = threadIdx.x >> 6;
    const int lane = threadIdx.x & 63;
    const int row  = blockIdx.x * 4 + wid;
    const float v = bf2f(Kk[(size_t)row * HD_ + lane]);
    float ss = v * v;
    #pragma unroll
    for (int off = 32; off; off >>= 1) ss += __shfl_xor(ss, off);
    if (lane == 0) kn2[row] = ss;
}

// ---------------------------------------------------------------------------
__global__ __launch_bounds__(256) void finalize_scale(const float* __restrict__ part,
                                                      const unsigned int* __restrict__ maxbits,
                                                      float* __restrict__ scal) {
    __shared__ float red[256];
    float ss = 0.f;
    for (int i = threadIdx.x; i < 1024; i += 256) ss += part[i];
    red[threadIdx.x] = ss;
    __syncthreads();
    for (int s = 128; s; s >>= 1) {
        if (threadIdx.x < (unsigned)s) red[threadIdx.x] += red[threadIdx.x + s];
        __syncthreads();
    }
    if (threadIdx.x == 0) {
        const float fro  = sqrtf(red[0]);
        const float inf2 = sqrtf(__uint_as_float(*maxbits));
        scal[0] = ALPHA_ / (fro * inf2);
    }
}

// ---------------------------------------------------------------------------
// bf16 MFMA flash attention (unchanged structure; epilogue now writes bf16).
// ---------------------------------------------------------------------------
__global__ __launch_bounds__(256) void attn_mfma(const unsigned short* __restrict__ Qb,
                                                 const unsigned short* __restrict__ Kb,
                                                 const unsigned short* __restrict__ Vtb,
                                                 const float* __restrict__ KN2,
                                                 const float* __restrict__ scal,
                                                 unsigned short* __restrict__ VALS) {
    __shared__ __align__(16) char lds[3 * 8192 + 256];
    char* Kt = lds;                  // [64 k][64 d] bf16, swizzled
    char* Vt = lds + 8192;           // [64 d][64 k] bf16, swizzled
    char* Pl = lds + 16384;          // 4 waves x [16 q][64 k] bf16, swizzled
    float* kn2s = (float*)(lds + 24576);

    const int t  = threadIdx.x;
    const int w  = t >> 6;
    const int l  = t & 63;
    const int g  = l >> 4;
    const int c  = l & 15;
    const int bh = blockIdx.y;
    const int qb = blockIdx.x;
    const float scale = scal[0];

    const int qrow = qb * 64 + w * 16 + c;
    const size_t qoff = ((size_t)bh * S_ + qrow) * HD_;
    const bf16x8 qf0 = *(const bf16x8*)&Qb[qoff + g * 8];
    const bf16x8 qf1 = *(const bf16x8*)&Qb[qoff + 32 + g * 8];

    f32x4 acc[4];
    #pragma unroll
    for (int dt = 0; dt < 4; ++dt)
        #pragma unroll
        for (int r = 0; r < 4; ++r) acc[dt][r] = 0.f;
    float mrun = -1e30f, lrun = 0.f;

    const size_t kbase  = (size_t)bh * S_ * HD_;
    const size_t vtbase = (size_t)bh * HD_ * S_;
    char* Pw = Pl + w * 2048;
    const int swc = (c & 7) << 4;

    for (int kt0 = 0; kt0 < S_; kt0 += 64) {
        __syncthreads();
        #pragma unroll
        for (int i = 0; i < 2; ++i) {
            const int idx = t + i * 256;
            const int r   = idx >> 3;
            const int cb  = (idx & 7) * 16;
            const int dst = r * 128 + (cb ^ ((r & 7) << 4));
            *(uint4*)(Kt + dst) = *(const uint4*)&Kb[kbase + (size_t)(kt0 + r) * HD_ + (cb >> 1)];
            *(uint4*)(Vt + dst) = *(const uint4*)&Vtb[vtbase + (size_t)r * S_ + kt0 + (cb >> 1)];
        }
        if (t < 64) kn2s[t] = KN2[(size_t)bh * S_ + kt0 + t];
        __syncthreads();

        float sl[16];
        #pragma unroll
        for (int kt = 0; kt < 4; ++kt) {
            const int r  = kt * 16 + c;
            const int sw = (r & 7) << 4;
            const bf16x8 ka0 = *(const bf16x8*)(Kt + r * 128 + ((g * 16) ^ sw));
            const bf16x8 ka1 = *(const bf16x8*)(Kt + r * 128 + ((64 + g * 16) ^ sw));
            f32x4 sacc = {0.f, 0.f, 0.f, 0.f};
            sacc = __builtin_amdgcn_mfma_f32_16x16x32_bf16(ka0, qf0, sacc, 0, 0, 0);
            sacc = __builtin_amdgcn_mfma_f32_16x16x32_bf16(ka1, qf1, sacc, 0, 0, 0);
            #pragma unroll
            for (int rg = 0; rg < 4; ++rg)
                sl[kt * 4 + rg] = scale * (2.f * sacc[rg] - kn2s[kt * 16 + g * 4 + rg]);
        }

        float pmax = sl[0];
        #pragma unroll
        for (int j = 1; j < 16; ++j) pmax = fmaxf(pmax, sl[j]);
        pmax = fmaxf(pmax, __shfl_xor(pmax, 16));
        pmax = fmaxf(pmax, __shfl_xor(pmax, 32));
        const float mnew = fmaxf(mrun, pmax);
        const float corr = __expf(mrun - mnew);
        lrun *= corr;
        #pragma unroll
        for (int dt = 0; dt < 4; ++dt)
            #pragma unroll
            for (int r = 0; r < 4; ++r) acc[dt][r] *= corr;
        float p[16];
        float psum = 0.f;
        #pragma unroll
        for (int j = 0; j < 16; ++j) { p[j] = __expf(sl[j] - mnew); psum += p[j]; }
        psum += __shfl_xor(psum, 16);
        psum += __shfl_xor(psum, 32);
        lrun += psum;
        mrun = mnew;

        #pragma unroll
        for (int kt = 0; kt < 4; ++kt) {
            const int cb = kt * 32 + g * 8;
            *(unsigned*)(Pw + c * 128 + (cb ^ swc))       = pack2bf(p[kt * 4 + 0], p[kt * 4 + 1]);
            *(unsigned*)(Pw + c * 128 + ((cb + 4) ^ swc)) = pack2bf(p[kt * 4 + 2], p[kt * 4 + 3]);
        }
        asm volatile("s_waitcnt lgkmcnt(0)" ::: "memory");
        __builtin_amdgcn_sched_barrier(0);

        const bf16x8 pa0 = *(const bf16x8*)(Pw + c * 128 + ((g * 16) ^ swc));
        const bf16x8 pa1 = *(const bf16x8*)(Pw + c * 128 + ((64 + g * 16) ^ swc));
        #pragma unroll
        for (int dt = 0; dt < 4; ++dt) {
            const int r  = dt * 16 + c;
            const int sw = (r & 7) << 4;
            const bf16x8 vb0 = *(const bf16x8*)(Vt + r * 128 + ((g * 16) ^ sw));
            const bf16x8 vb1 = *(const bf16x8*)(Vt + r * 128 + ((64 + g * 16) ^ sw));
            acc[dt] = __builtin_amdgcn_mfma_f32_16x16x32_bf16(pa0, vb0, acc[dt], 0, 0, 0);
            acc[dt] = __builtin_amdgcn_mfma_f32_16x16x32_bf16(pa1, vb1, acc[dt], 0, 0, 0);
        }
    }

    // epilogue -> bf16 VAL [B,S,E]
    const int b = bh >> 3, h = bh & 7;
    #pragma unroll
    for (int reg = 0; reg < 4; ++reg) {
        const float lq  = __shfl(lrun, g * 4 + reg);
        const float inv = 1.0f / lq;
        const int qg = qb * 64 + w * 16 + g * 4 + reg;
        unsigned short* dst = &VALS[((size_t)b * S_ + qg) * E_ + h * HD_];
        #pragma unroll
        for (int dt = 0; dt < 4; ++dt)
            dst[dt * 16 + c] = f2bf(acc[dt][reg] * inv);
    }
}

// ---------------------------------------------------------------------------
extern "C" void kernel_launch(void* const* d_in, const int* in_sizes, int n_in,
                              void* d_out, int out_size, void* d_ws, size_t ws_size,
                              hipStream_t stream) {
    const float* x    = (const float*)d_in[0];
    const float* Wqkv = (const float*)d_in[1];
    const float* bqkv = (const float*)d_in[2];
    const float* Wo   = (const float*)d_in[3];
    const float* bo   = (const float*)d_in[4];
    float* out = (float*)d_out;

    char* ws = (char*)d_ws;
    unsigned short* Qb    = (unsigned short*)(ws);                        // 8 MB
    unsigned short* Kb    = (unsigned short*)(ws + ((size_t) 8 << 20));   // 8 MB
    unsigned short* Vtb   = (unsigned short*)(ws + ((size_t)16 << 20));   // 8 MB
    unsigned short* VALb  = (unsigned short*)(ws + ((size_t)24 << 20));   // 8 MB
    unsigned short* xbf   = (unsigned short*)(ws + ((size_t)32 << 20));   // 8 MB
    unsigned short* Wqkvb = (unsigned short*)(ws + ((size_t)40 << 20));   // 1.5 MB
    unsigned short* Wob   = (unsigned short*)(ws + ((size_t)42 << 20));   // 0.5 MB
    float* KN2  = (float*)(ws + ((size_t)43 << 20));                      // 256 KB
    float* PART = (float*)(ws + ((size_t)43 << 20) + (256 << 10));        // 4 KB
    float* SCAL = (float*)(ws + ((size_t)43 << 20) + (260 << 10));
    unsigned int* MAXB = (unsigned int*)(SCAL + 1);

    hipMemsetAsync(MAXB, 0, sizeof(unsigned int), stream);

    // 0) fp32 -> bf16 conversions
    cvt_bf16<<<2048, 256, 0, stream>>>(x,    xbf,   M_ * D_ / 8);
    cvt_bf16<<< 384, 256, 0, stream>>>(Wqkv, Wqkvb, 3 * E_ * D_ / 8);
    cvt_bf16<<< 128, 256, 0, stream>>>(Wo,   Wob,   E_ * E_ / 8);

    // 1) QKV projection (bf16 MFMA) -> Q,K [bh][S][64], V^T [bh][64][S]
    gemm_mfma<3 * E_, 0><<<dim3(12, 64), 256, 0, stream>>>(xbf, Wqkvb, bqkv, Qb, Kb, Vtb);

    // 2) normalizer scalars + key norms
    xrow_norm_max<<<2048, 256, 0, stream>>>(x, MAXB);
    q_sumsq_partial<<<1024, 256, 0, stream>>>(Qb, PART);
    k_norm2_kernel<<<16384, 256, 0, stream>>>(Kb, KN2);
    finalize_scale<<<1, 256, 0, stream>>>(PART, MAXB, SCAL);

    // 3) MFMA flash attention -> VAL bf16 [B,S,E]
    attn_mfma<<<dim3(S_ / 64, B_ * H_), 256, 0, stream>>>(Qb, Kb, Vtb, KN2, SCAL, VALb);

    // 4) output projection (bf16 MFMA, fp32 out)
    gemm_mfma<E_, 1><<<dim3(4, 64), 256, 0, stream>>>(VALb, Wob, bo, out, nullptr, nullptr);
}

// Round 7
// 269.728 us; speedup vs baseline: 5.7598x; 1.0280x over previous
//
#include <hip/hip_runtime.h>
#include <math.h>

#define B_ 4
#define S_ 2048
#define D_ 512
#define E_ 512
#define H_ 8
#define HD_ 64
#define ALPHA_ 1.0f
#define M_ (B_*S_)   // 8192
#define LOG2E_ 1.44269504088896340736f

typedef __attribute__((ext_vector_type(8))) short bf16x8;
typedef __attribute__((ext_vector_type(4))) float f32x4;

__device__ inline float bf2f(unsigned short u) {
    return __uint_as_float(((unsigned)u) << 16);
}
__device__ inline unsigned short f2bf(float f) {
    unsigned u = __float_as_uint(f);
    u = (u + 0x7FFF + ((u >> 16) & 1)) >> 16;   // RNE
    return (unsigned short)u;
}
__device__ inline unsigned pack2bf(float a, float b) {
    return (unsigned)f2bf(a) | ((unsigned)f2bf(b) << 16);
}

// ---------------------------------------------------------------------------
// x prep: fp32 x -> bf16 xbf AND max ||x_row||^2 (atomicMax on uint bits).
// One wave per row (64 lanes x 8 elems), 4 rows/block, grid 2048.
// ---------------------------------------------------------------------------
__global__ __launch_bounds__(256) void x_prep(const float* __restrict__ x,
                                              unsigned short* __restrict__ xbf,
                                              unsigned int* __restrict__ maxbits) {
    const int wid  = threadIdx.x >> 6;
    const int lane = threadIdx.x & 63;
    const int row  = blockIdx.x * 4 + wid;
    const float* xr = &x[(size_t)row * D_ + lane * 8];
    const float4 a = *(const float4*)xr;
    const float4 b = *(const float4*)(xr + 4);
    float ss = a.x*a.x + a.y*a.y + a.z*a.z + a.w*a.w
             + b.x*b.x + b.y*b.y + b.z*b.z + b.w*b.w;
    uint4 o;
    o.x = pack2bf(a.x, a.y); o.y = pack2bf(a.z, a.w);
    o.z = pack2bf(b.x, b.y); o.w = pack2bf(b.z, b.w);
    *(uint4*)&xbf[(size_t)row * D_ + lane * 8] = o;
    #pragma unroll
    for (int off = 32; off; off >>= 1) ss += __shfl_xor(ss, off);
    if (lane == 0) atomicMax(maxbits, __float_as_uint(ss));
}

// ---------------------------------------------------------------------------
// both weight matrices fp32 -> bf16 in one launch (512 blocks)
// ---------------------------------------------------------------------------
__global__ __launch_bounds__(256) void w_cvt(const float* __restrict__ Wqkv,
                                             const float* __restrict__ Wo,
                                             unsigned short* __restrict__ Wqkvb,
                                             unsigned short* __restrict__ Wob) {
    const int i  = blockIdx.x * 256 + threadIdx.x;
    const int nq = 3 * E_ * D_ / 8;                 // 98304
    const float* src; unsigned short* dst; int j;
    if (i < nq) { src = Wqkv; dst = Wqkvb; j = i; }
    else        { src = Wo;   dst = Wob;   j = i - nq; }
    const float4 a = *(const float4*)&src[(size_t)j * 8];
    const float4 b = *(const float4*)&src[(size_t)j * 8 + 4];
    uint4 o;
    o.x = pack2bf(a.x, a.y); o.y = pack2bf(a.z, a.w);
    o.z = pack2bf(b.x, b.y); o.w = pack2bf(b.z, b.w);
    *(uint4*)&dst[(size_t)j * 8] = o;
}

// ---------------------------------------------------------------------------
// bf16 MFMA GEMM: C[M,N] = A[M,512] @ W[N,512]^T + bias[N]
// 128x128 tile, BK=64, 4 waves (2x2). LDS XOR-swizzled (byte ^= (row&7)<<4).
// MODE 0: scatter bf16 -> Q,K [bh][S][64], V^T [bh][64][S]; + per-block
//         sum(q^2) partial -> part[bid] (deterministic LDS tree).
// MODE 1: fp32 C row-major [M][N]
// ---------------------------------------------------------------------------
template<int N, int MODE>
__global__ __launch_bounds__(256) void gemm_mfma(const unsigned short* __restrict__ Abf,
                                                 const unsigned short* __restrict__ Wbf,
                                                 const float* __restrict__ bias,
                                                 void* __restrict__ out0,
                                                 void* __restrict__ out1,
                                                 void* __restrict__ out2,
                                                 float* __restrict__ part) {
    __shared__ __align__(16) char At[16384];
    __shared__ __align__(16) char Wt[16384];

    const int t  = threadIdx.x;
    const int w  = t >> 6;
    const int l  = t & 63;
    const int g  = l >> 4;
    const int c  = l & 15;
    const int wm = w >> 1;
    const int wn = w & 1;
    const int m0 = blockIdx.y * 128;
    const int n0 = blockIdx.x * 128;

    f32x4 acc[4][4];
    #pragma unroll
    for (int i = 0; i < 4; ++i)
        #pragma unroll
        for (int j = 0; j < 4; ++j)
            #pragma unroll
            for (int r = 0; r < 4; ++r) acc[i][j][r] = 0.f;

    for (int k0 = 0; k0 < 512; k0 += 64) {
        __syncthreads();
        #pragma unroll
        for (int i = 0; i < 4; ++i) {
            const int idx = t + i * 256;
            const int r   = idx >> 3;
            const int j   = idx & 7;
            const int dst = r * 128 + ((j * 16) ^ ((r & 7) << 4));
            *(uint4*)(At + dst) = *(const uint4*)&Abf[(size_t)(m0 + r) * 512 + k0 + j * 8];
            *(uint4*)(Wt + dst) = *(const uint4*)&Wbf[(size_t)(n0 + r) * 512 + k0 + j * 8];
        }
        __syncthreads();

        bf16x8 af[4][2], wf[4][2];
        #pragma unroll
        for (int mt = 0; mt < 4; ++mt) {
            const int row = wm * 64 + mt * 16 + c;
            const int sw  = (row & 7) << 4;
            #pragma unroll
            for (int kc = 0; kc < 2; ++kc)
                af[mt][kc] = *(const bf16x8*)(At + row * 128 + (((kc * 4 + g) * 16) ^ sw));
        }
        #pragma unroll
        for (int nt = 0; nt < 4; ++nt) {
            const int row = wn * 64 + nt * 16 + c;
            const int sw  = (row & 7) << 4;
            #pragma unroll
            for (int kc = 0; kc < 2; ++kc)
                wf[nt][kc] = *(const bf16x8*)(Wt + row * 128 + (((kc * 4 + g) * 16) ^ sw));
        }
        #pragma unroll
        for (int mt = 0; mt < 4; ++mt)
            #pragma unroll
            for (int nt = 0; nt < 4; ++nt) {
                acc[mt][nt] = __builtin_amdgcn_mfma_f32_16x16x32_bf16(af[mt][0], wf[nt][0], acc[mt][nt], 0, 0, 0);
                acc[mt][nt] = __builtin_amdgcn_mfma_f32_16x16x32_bf16(af[mt][1], wf[nt][1], acc[mt][nt], 0, 0, 0);
            }
    }

    float qss = 0.f;
    #pragma unroll
    for (int mt = 0; mt < 4; ++mt) {
        #pragma unroll
        for (int reg = 0; reg < 4; ++reg) {
            const int m = m0 + wm * 64 + mt * 16 + g * 4 + reg;
            #pragma unroll
            for (int nt = 0; nt < 4; ++nt) {
                const int n = n0 + wn * 64 + nt * 16 + c;
                const float val = acc[mt][nt][reg] + bias[n];
                if (MODE == 0) {
                    const int h = n / 192;
                    const int u = n - h * 192;
                    const int d = u & 63;
                    const int b = m >> 11;
                    const int s = m & 2047;
                    const unsigned short bv = f2bf(val);
                    if (u < 64) {
                        qss = fmaf(val, val, qss);
                        ((unsigned short*)out0)[(((size_t)b * H_ + h) * S_ + s) * HD_ + d] = bv;
                    } else if (u < 128) {
                        ((unsigned short*)out1)[(((size_t)b * H_ + h) * S_ + s) * HD_ + d] = bv;
                    } else {
                        ((unsigned short*)out2)[(((size_t)b * H_ + h) * HD_ + d) * S_ + s] = bv;
                    }
                } else {
                    ((float*)out0)[(size_t)m * N + n] = val;
                }
            }
        }
    }

    if (MODE == 0) {
        // deterministic per-block sum(q^2) -> part[bid]
        __syncthreads();
        float* red = (float*)At;
        red[t] = qss;
        __syncthreads();
        for (int s = 128; s; s >>= 1) {
            if (t < s) red[t] += red[t + s];
            __syncthreads();
        }
        if (t == 0) part[blockIdx.y * gridDim.x + blockIdx.x] = red[0];
    }
}

// ---------------------------------------------------------------------------
// finalize: scal = ALPHA * log2(e) / (sqrt(sum q^2) * sqrt(max row norm^2))
// part has 768 entries (one per QKV GEMM block), fixed-tree sum.
// ---------------------------------------------------------------------------
__global__ __launch_bounds__(256) void finalize_scale(const float* __restrict__ part,
                                                      const unsigned int* __restrict__ maxbits,
                                                      float* __restrict__ scal) {
    __shared__ float red[256];
    float ss = 0.f;
    for (int i = threadIdx.x; i < 768; i += 256) ss += part[i];
    red[threadIdx.x] = ss;
    __syncthreads();
    for (int s = 128; s; s >>= 1) {
        if (threadIdx.x < (unsigned)s) red[threadIdx.x] += red[threadIdx.x + s];
        __syncthreads();
    }
    if (threadIdx.x == 0) {
        const float fro  = sqrtf(red[0]);
        const float inf2 = sqrtf(__uint_as_float(*maxbits));
        scal[0] = ALPHA_ * LOG2E_ / (fro * inf2);
    }
}

// ---------------------------------------------------------------------------
// per-key scale2*||k||^2 from bf16 K (pre-scaled for the attn inner loop)
// ---------------------------------------------------------------------------
__global__ __launch_bounds__(256) void k_norm2_scaled(const unsigned short* __restrict__ Kk,
                                                      const float* __restrict__ scal,
                                                      float* __restrict__ kn2) {
    const int wid  = threadIdx.x >> 6;
    const int lane = threadIdx.x & 63;
    const int row  = blockIdx.x * 4 + wid;
    const float v = bf2f(Kk[(size_t)row * HD_ + lane]);
    float ss = v * v;
    #pragma unroll
    for (int off = 32; off; off >>= 1) ss += __shfl_xor(ss, off);
    if (lane == 0) kn2[row] = scal[0] * ss;
}

// ---------------------------------------------------------------------------
// bf16 MFMA flash attention, exp2 domain, defer-max (T13), issue-early
// reg-staged K/V double-buffer (T14). 4 waves, 64 q/block, KV tile 64,
// 2 tiles per loop iter. All LDS XOR-swizzled (byte ^= (row&7)<<4).
// ---------------------------------------------------------------------------
__global__ __launch_bounds__(256) void attn_mfma(const unsigned short* __restrict__ Qb,
                                                 const unsigned short* __restrict__ Kb,
                                                 const unsigned short* __restrict__ Vtb,
                                                 const float* __restrict__ KN2S,
                                                 const float* __restrict__ scal,
                                                 unsigned short* __restrict__ VALS) {
    __shared__ __align__(16) char lds[24832];
    char* Kt = lds;                  // [64 k][64 d] bf16, swizzled
    char* Vt = lds + 8192;           // [64 d][64 k] bf16, swizzled
    char* Pl = lds + 16384;          // 4 waves x [16 q][64 k] bf16, swizzled
    float* kn2s = (float*)(lds + 24576);

    const int t  = threadIdx.x;
    const int w  = t >> 6;
    const int l  = t & 63;
    const int g  = l >> 4;
    const int c  = l & 15;
    const int bh = blockIdx.y;
    const int qb = blockIdx.x;
    const float ts2 = 2.0f * scal[0];

    const int qrow = qb * 64 + w * 16 + c;
    const size_t qoff = ((size_t)bh * S_ + qrow) * HD_;
    const bf16x8 qf0 = *(const bf16x8*)&Qb[qoff + g * 8];
    const bf16x8 qf1 = *(const bf16x8*)&Qb[qoff + 32 + g * 8];

    f32x4 acc[4];
    #pragma unroll
    for (int dt = 0; dt < 4; ++dt)
        #pragma unroll
        for (int r = 0; r < 4; ++r) acc[dt][r] = 0.f;
    float mrun = -1e30f, lrun = 0.f;

    const size_t kbase  = (size_t)bh * S_ * HD_;
    const size_t vtbase = (size_t)bh * HD_ * S_;
    const float* kn2g = &KN2S[(size_t)bh * S_];
    char* Pw = Pl + w * 2048;
    const int swc = (c & 7) << 4;

    // staging geometry: thread t handles row rr (and rr+32), 16B col jj*2
    const int rr = t >> 3;
    const int jj = (t & 7) * 8;
    const size_t koff0 = kbase + (size_t)rr * HD_ + jj;
    const size_t voff0 = vtbase + (size_t)rr * S_ + jj;
    const int d0 = rr * 128 + ((jj * 2) ^ ((rr & 7) << 4));

    uint4 kA0, kA1, vA0, vA1, kB0, kB1, vB0, vB1;
    float nA, nB;

#define LOADT(K0, K1, V0, V1, NN, off) do {                                   \
        K0 = *(const uint4*)&Kb[koff0 + (size_t)(off) * HD_];                 \
        K1 = *(const uint4*)&Kb[koff0 + (size_t)((off) + 32) * HD_];          \
        V0 = *(const uint4*)&Vtb[voff0 + (off)];                              \
        V1 = *(const uint4*)&Vtb[voff0 + (size_t)32 * S_ + (off)];            \
        NN = (t < 64) ? kn2g[(off) + t] : 0.f;                                \
    } while (0)

#define STORET(K0, K1, V0, V1, NN) do {                                       \
        *(uint4*)(Kt + d0) = K0; *(uint4*)(Kt + d0 + 4096) = K1;              \
        *(uint4*)(Vt + d0) = V0; *(uint4*)(Vt + d0 + 4096) = V1;              \
        if (t < 64) kn2s[t] = NN;                                             \
    } while (0)

    auto compute_tile = [&]() {
        float sl[16];
        #pragma unroll
        for (int kt = 0; kt < 4; ++kt) {
            const int r  = kt * 16 + c;
            const int sw = (r & 7) << 4;
            const bf16x8 ka0 = *(const bf16x8*)(Kt + r * 128 + ((g * 16) ^ sw));
            const bf16x8 ka1 = *(const bf16x8*)(Kt + r * 128 + ((64 + g * 16) ^ sw));
            f32x4 sacc = {0.f, 0.f, 0.f, 0.f};
            sacc = __builtin_amdgcn_mfma_f32_16x16x32_bf16(ka0, qf0, sacc, 0, 0, 0);
            sacc = __builtin_amdgcn_mfma_f32_16x16x32_bf16(ka1, qf1, sacc, 0, 0, 0);
            #pragma unroll
            for (int rg = 0; rg < 4; ++rg)
                sl[kt * 4 + rg] = fmaf(sacc[rg], ts2, -kn2s[kt * 16 + g * 4 + rg]);
        }
        float pmax = sl[0];
        #pragma unroll
        for (int j = 1; j < 16; ++j) pmax = fmaxf(pmax, sl[j]);
        pmax = fmaxf(pmax, __shfl_xor(pmax, 16));
        pmax = fmaxf(pmax, __shfl_xor(pmax, 32));
        if (!__all(pmax <= mrun + 8.f)) {            // T13: rare rescale
            const float mnew = fmaxf(mrun, pmax);
            const float cf = exp2f(mrun - mnew);
            lrun *= cf;
            #pragma unroll
            for (int dt = 0; dt < 4; ++dt)
                #pragma unroll
                for (int r = 0; r < 4; ++r) acc[dt][r] *= cf;
            mrun = mnew;
        }
        float p[16];
        float psum = 0.f;
        #pragma unroll
        for (int j = 0; j < 16; ++j) { p[j] = exp2f(sl[j] - mrun); psum += p[j]; }
        psum += __shfl_xor(psum, 16);
        psum += __shfl_xor(psum, 32);
        lrun += psum;

        #pragma unroll
        for (int kt = 0; kt < 4; ++kt) {
            uint2 pk;
            pk.x = pack2bf(p[kt * 4 + 0], p[kt * 4 + 1]);
            pk.y = pack2bf(p[kt * 4 + 2], p[kt * 4 + 3]);
            const int cb = kt * 32 + g * 8;
            *(uint2*)(Pw + c * 128 + (cb ^ swc)) = pk;
        }
        asm volatile("s_waitcnt lgkmcnt(0)" ::: "memory");
        __builtin_amdgcn_sched_barrier(0);

        const bf16x8 pa0 = *(const bf16x8*)(Pw + c * 128 + ((g * 16) ^ swc));
        const bf16x8 pa1 = *(const bf16x8*)(Pw + c * 128 + ((64 + g * 16) ^ swc));
        #pragma unroll
        for (int dt = 0; dt < 4; ++dt) {
            const int r  = dt * 16 + c;
            const int sw = (r & 7) << 4;
            const bf16x8 vb0 = *(const bf16x8*)(Vt + r * 128 + ((g * 16) ^ sw));
            const bf16x8 vb1 = *(const bf16x8*)(Vt + r * 128 + ((64 + g * 16) ^ sw));
            acc[dt] = __builtin_amdgcn_mfma_f32_16x16x32_bf16(pa0, vb0, acc[dt], 0, 0, 0);
            acc[dt] = __builtin_amdgcn_mfma_f32_16x16x32_bf16(pa1, vb1, acc[dt], 0, 0, 0);
        }
    };

    LOADT(kA0, kA1, vA0, vA1, nA, 0);
    for (int kt0 = 0; kt0 < S_; kt0 += 128) {
        __syncthreads();
        STORET(kA0, kA1, vA0, vA1, nA);
        __syncthreads();
        LOADT(kB0, kB1, vB0, vB1, nB, kt0 + 64);   // issue-early, lands during compute
        compute_tile();
        __syncthreads();
        STORET(kB0, kB1, vB0, vB1, nB);
        __syncthreads();
        if (kt0 + 128 < S_) LOADT(kA0, kA1, vA0, vA1, nA, kt0 + 128);
        compute_tile();
    }
#undef LOADT
#undef STORET

    // epilogue -> bf16 VAL [B,S,E]
    const int b = bh >> 3, h = bh & 7;
    #pragma unroll
    for (int reg = 0; reg < 4; ++reg) {
        const float lq  = __shfl(lrun, g * 4 + reg);
        const float inv = 1.0f / lq;
        const int qg = qb * 64 + w * 16 + g * 4 + reg;
        unsigned short* dst = &VALS[((size_t)b * S_ + qg) * E_ + h * HD_];
        #pragma unroll
        for (int dt = 0; dt < 4; ++dt)
            dst[dt * 16 + c] = f2bf(acc[dt][reg] * inv);
    }
}

// ---------------------------------------------------------------------------
extern "C" void kernel_launch(void* const* d_in, const int* in_sizes, int n_in,
                              void* d_out, int out_size, void* d_ws, size_t ws_size,
                              hipStream_t stream) {
    const float* x    = (const float*)d_in[0];
    const float* Wqkv = (const float*)d_in[1];
    const float* bqkv = (const float*)d_in[2];
    const float* Wo   = (const float*)d_in[3];
    const float* bo   = (const float*)d_in[4];
    float* out = (float*)d_out;

    char* ws = (char*)d_ws;
    unsigned short* Qb    = (unsigned short*)(ws);                        // 8 MB
    unsigned short* Kb    = (unsigned short*)(ws + ((size_t) 8 << 20));   // 8 MB
    unsigned short* Vtb   = (unsigned short*)(ws + ((size_t)16 << 20));   // 8 MB
    unsigned short* VALb  = (unsigned short*)(ws + ((size_t)24 << 20));   // 8 MB
    unsigned short* xbf   = (unsigned short*)(ws + ((size_t)32 << 20));   // 8 MB
    unsigned short* Wqkvb = (unsigned short*)(ws + ((size_t)40 << 20));   // 1.5 MB
    unsigned short* Wob   = (unsigned short*)(ws + ((size_t)42 << 20));   // 0.5 MB
    float* KN2S = (float*)(ws + ((size_t)43 << 20));                      // 256 KB
    float* PART = (float*)(ws + ((size_t)43 << 20) + (256 << 10));        // 3 KB
    float* SCAL = (float*)(ws + ((size_t)43 << 20) + (260 << 10));
    unsigned int* MAXB = (unsigned int*)(SCAL + 1);

    hipMemsetAsync(MAXB, 0, sizeof(unsigned int), stream);

    // 0) x -> bf16 + max row-norm; weights -> bf16
    x_prep<<<2048, 256, 0, stream>>>(x, xbf, MAXB);
    w_cvt<<<512, 256, 0, stream>>>(Wqkv, Wo, Wqkvb, Wob);

    // 1) QKV projection (bf16 MFMA) + sum(q^2) partials
    gemm_mfma<3 * E_, 0><<<dim3(12, 64), 256, 0, stream>>>(xbf, Wqkvb, bqkv, Qb, Kb, Vtb, PART);

    // 2) normalizer scalar, then pre-scaled key norms
    finalize_scale<<<1, 256, 0, stream>>>(PART, MAXB, SCAL);
    k_norm2_scaled<<<16384, 256, 0, stream>>>(Kb, SCAL, KN2S);

    // 3) MFMA flash attention -> VAL bf16 [B,S,E]
    attn_mfma<<<dim3(S_ / 64, B_ * H_), 256, 0, stream>>>(Qb, Kb, Vtb, KN2S, SCAL, VALb);

    // 4) output projection (bf16 MFMA, fp32 out)
    gemm_mfma<E_, 1><<<dim3(4, 64), 256, 0, stream>>>(VALb, Wob, bo, out, nullptr, nullptr, nullptr);
}

// Round 9
// 162.119 us; speedup vs baseline: 9.5829x; 1.6638x over previous
//
#include <hip/hip_runtime.h>
#include <hip/hip_bf16.h>
#include <math.h>

#define B_ 4
#define S_ 2048
#define D_ 512
#define E_ 512
#define H_ 8
#define HD_ 64
#define ALPHA_ 1.0f
#define M_ (B_*S_)   // 8192
#define LOG2E_ 1.44269504088896340736f

typedef __attribute__((ext_vector_type(8))) short bf16x8;
typedef __attribute__((ext_vector_type(4))) float f32x4;

__device__ inline unsigned short f2bf(float f) {
    union { __hip_bfloat16 h; unsigned short u; } cv;
    cv.h = __float2bfloat16(f);
    return cv.u;
}
__device__ inline unsigned pack2bf(float a, float b) {
    union { __hip_bfloat162 h; unsigned u; } cv;
    cv.h = __float22bfloat162_rn(make_float2(a, b));
    return cv.u;
}

// ---------------------------------------------------------------------------
// prep: blocks 0..2047: x -> bf16 + per-block max ||x_row||^2 (no atomics)
//       blocks 2048..2559: Wqkv,Wo -> bf16
// ---------------------------------------------------------------------------
__global__ __launch_bounds__(256) void prep(const float* __restrict__ x,
                                            const float* __restrict__ Wqkv,
                                            const float* __restrict__ Wo,
                                            unsigned short* __restrict__ xbf,
                                            unsigned short* __restrict__ Wqkvb,
                                            unsigned short* __restrict__ Wob,
                                            float* __restrict__ xmax) {
    const int t   = threadIdx.x;
    const int bid = blockIdx.x;
    if (bid < 2048) {
        __shared__ float red[4];
        const int wid = t >> 6, lane = t & 63;
        const int row = bid * 4 + wid;
        const float* xr = &x[(size_t)row * D_ + lane * 8];
        const float4 a = *(const float4*)xr;
        const float4 b = *(const float4*)(xr + 4);
        float ss = a.x*a.x + a.y*a.y + a.z*a.z + a.w*a.w
                 + b.x*b.x + b.y*b.y + b.z*b.z + b.w*b.w;
        uint4 o;
        o.x = pack2bf(a.x, a.y); o.y = pack2bf(a.z, a.w);
        o.z = pack2bf(b.x, b.y); o.w = pack2bf(b.z, b.w);
        *(uint4*)&xbf[(size_t)row * D_ + lane * 8] = o;
        #pragma unroll
        for (int off = 32; off; off >>= 1) ss += __shfl_xor(ss, off);
        if (lane == 0) red[wid] = ss;
        __syncthreads();
        if (t == 0)
            xmax[bid] = fmaxf(fmaxf(red[0], red[1]), fmaxf(red[2], red[3]));
    } else {
        const int i  = (bid - 2048) * 256 + t;       // 0..131071
        const int nq = 3 * E_ * D_ / 8;              // 98304
        const float* src; unsigned short* dst; int j;
        if (i < nq) { src = Wqkv; dst = Wqkvb; j = i; }
        else        { src = Wo;   dst = Wob;   j = i - nq; }
        const float4 a = *(const float4*)&src[(size_t)j * 8];
        const float4 b = *(const float4*)&src[(size_t)j * 8 + 4];
        uint4 o;
        o.x = pack2bf(a.x, a.y); o.y = pack2bf(a.z, a.w);
        o.z = pack2bf(b.x, b.y); o.w = pack2bf(b.z, b.w);
        *(uint4*)&dst[(size_t)j * 8] = o;
    }
}

// ---------------------------------------------------------------------------
// bf16 MFMA GEMM: C[M,N] = A[M,512] @ W[N,512]^T + bias[N]
// 128x128 tile, BK=64, 4 waves (2x2). LDS XOR-swizzled (byte ^= (row&7)<<4).
// MODE 0: per-64-col-half class (q/k/v): scatter bf16 Q,K [bh][S][64],
//         V^T [bh][64][S] (8B packed); + sum(q^2) partials; + per-key ||k||^2.
// MODE 1: fp32 C row-major [M][N]
// ---------------------------------------------------------------------------
template<int N, int MODE>
__global__ __launch_bounds__(256) void gemm_mfma(const unsigned short* __restrict__ Abf,
                                                 const unsigned short* __restrict__ Wbf,
                                                 const float* __restrict__ bias,
                                                 void* __restrict__ out0,
                                                 void* __restrict__ out1,
                                                 void* __restrict__ out2,
                                                 float* __restrict__ part,
                                                 float* __restrict__ kn2) {
    __shared__ __align__(16) char At[16384];
    __shared__ __align__(16) char Wt[16384];

    const int t  = threadIdx.x;
    const int w  = t >> 6;
    const int l  = t & 63;
    const int g  = l >> 4;
    const int c  = l & 15;
    const int wm = w >> 1;
    const int wn = w & 1;
    const int m0 = blockIdx.y * 128;
    const int n0 = blockIdx.x * 128;

    f32x4 acc[4][4];
    #pragma unroll
    for (int i = 0; i < 4; ++i)
        #pragma unroll
        for (int j = 0; j < 4; ++j)
            #pragma unroll
            for (int r = 0; r < 4; ++r) acc[i][j][r] = 0.f;

    for (int k0 = 0; k0 < 512; k0 += 64) {
        __syncthreads();
        #pragma unroll
        for (int i = 0; i < 4; ++i) {
            const int idx = t + i * 256;
            const int r   = idx >> 3;
            const int j   = idx & 7;
            const int dst = r * 128 + ((j * 16) ^ ((r & 7) << 4));
            *(uint4*)(At + dst) = *(const uint4*)&Abf[(size_t)(m0 + r) * 512 + k0 + j * 8];
            *(uint4*)(Wt + dst) = *(const uint4*)&Wbf[(size_t)(n0 + r) * 512 + k0 + j * 8];
        }
        __syncthreads();

        bf16x8 af[4][2], wf[4][2];
        #pragma unroll
        for (int mt = 0; mt < 4; ++mt) {
            const int row = wm * 64 + mt * 16 + c;
            const int sw  = (row & 7) << 4;
            #pragma unroll
            for (int kc = 0; kc < 2; ++kc)
                af[mt][kc] = *(const bf16x8*)(At + row * 128 + (((kc * 4 + g) * 16) ^ sw));
        }
        #pragma unroll
        for (int nt = 0; nt < 4; ++nt) {
            const int row = wn * 64 + nt * 16 + c;
            const int sw  = (row & 7) << 4;
            #pragma unroll
            for (int kc = 0; kc < 2; ++kc)
                wf[nt][kc] = *(const bf16x8*)(Wt + row * 128 + (((kc * 4 + g) * 16) ^ sw));
        }
        #pragma unroll
        for (int mt = 0; mt < 4; ++mt)
            #pragma unroll
            for (int nt = 0; nt < 4; ++nt) {
                acc[mt][nt] = __builtin_amdgcn_mfma_f32_16x16x32_bf16(af[mt][0], wf[nt][0], acc[mt][nt], 0, 0, 0);
                acc[mt][nt] = __builtin_amdgcn_mfma_f32_16x16x32_bf16(af[mt][1], wf[nt][1], acc[mt][nt], 0, 0, 0);
            }
    }

    if (MODE == 1) {
        #pragma unroll
        for (int mt = 0; mt < 4; ++mt)
            #pragma unroll
            for (int reg = 0; reg < 4; ++reg) {
                const int m = m0 + wm * 64 + mt * 16 + g * 4 + reg;
                #pragma unroll
                for (int nt = 0; nt < 4; ++nt) {
                    const int n = n0 + wn * 64 + nt * 16 + c;
                    ((float*)out0)[(size_t)m * N + n] = acc[mt][nt][reg] + bias[n];
                }
            }
        return;
    }

    // ---- MODE 0: q/k/v scatter by 64-col half ----
    const int hb  = 2 * blockIdx.x + wn;     // half index 0..23
    const int cls = hb % 3;                  // 0=q, 1=k, 2=v
    const int h   = hb / 3;
    const int b   = m0 >> 11;
    const int s0w = (m0 & 2047) + wm * 64;   // base s of this wave
    const size_t bhS = ((size_t)b * H_ + h) * S_;

    float kp[4][4];
    #pragma unroll
    for (int i = 0; i < 4; ++i)
        #pragma unroll
        for (int j = 0; j < 4; ++j) kp[i][j] = 0.f;

    if (cls == 2) {
        unsigned short* Vt_ = (unsigned short*)out2;
        #pragma unroll
        for (int nt = 0; nt < 4; ++nt) {
            const int n = n0 + wn * 64 + nt * 16 + c;
            const float bv = bias[n];
            const int d = nt * 16 + c;
            unsigned short* dbase = Vt_ + (((size_t)b * H_ + h) * HD_ + d) * S_ + s0w;
            #pragma unroll
            for (int mt = 0; mt < 4; ++mt) {
                uint2 pk;
                pk.x = pack2bf(acc[mt][nt][0] + bv, acc[mt][nt][1] + bv);
                pk.y = pack2bf(acc[mt][nt][2] + bv, acc[mt][nt][3] + bv);
                *(uint2*)&dbase[mt * 16 + g * 4] = pk;
            }
        }
    } else {
        unsigned short* dst0 = (cls == 0) ? (unsigned short*)out0 : (unsigned short*)out1;
        #pragma unroll
        for (int nt = 0; nt < 4; ++nt) {
            const int n = n0 + wn * 64 + nt * 16 + c;
            const float bv = bias[n];
            const int d = nt * 16 + c;
            #pragma unroll
            for (int mt = 0; mt < 4; ++mt)
                #pragma unroll
                for (int reg = 0; reg < 4; ++reg) {
                    const int s = s0w + mt * 16 + g * 4 + reg;
                    const float val = acc[mt][nt][reg] + bv;
                    kp[mt][reg] = fmaf(val, val, kp[mt][reg]);
                    dst0[(bhS + s) * HD_ + d] = f2bf(val);
                }
        }
    }

    __syncthreads();
    if (cls == 1) {
        // per-key ||k||^2: LDS transpose-reduce over the 16 c-lanes
        float* scratch = (float*)At + wm * 1088;       // 64 lanes x 17 floats
        #pragma unroll
        for (int i = 0; i < 16; ++i) scratch[l * 17 + i] = kp[i >> 2][i & 3];
        asm volatile("s_waitcnt lgkmcnt(0)" ::: "memory");
        __builtin_amdgcn_sched_barrier(0);
        float sum = 0.f;
        #pragma unroll
        for (int cc = 0; cc < 16; ++cc)
            sum += scratch[(g * 16 + cc) * 17 + c];
        const int s = s0w + (c >> 2) * 16 + g * 4 + (c & 3);
        kn2[bhS + s] = sum;
    }
    __syncthreads();

    // deterministic per-block sum(q^2) partial (q-class threads hold it in kp)
    float qss = 0.f;
    if (cls == 0) {
        #pragma unroll
        for (int i = 0; i < 4; ++i)
            #pragma unroll
            for (int j = 0; j < 4; ++j) qss += kp[i][j];
    }
    float* red = (float*)At;
    red[t] = qss;
    __syncthreads();
    for (int s = 128; s; s >>= 1) {
        if (t < s) red[t] += red[t + s];
        __syncthreads();
    }
    if (t == 0) part[blockIdx.y * gridDim.x + blockIdx.x] = red[0];
}

// ---------------------------------------------------------------------------
// finalize: scal = ALPHA*log2(e) / (sqrt(sum q^2) * sqrt(max row norm^2))
// ---------------------------------------------------------------------------
__global__ __launch_bounds__(256) void finalize_scale(const float* __restrict__ part,
                                                      const float* __restrict__ xmax,
                                                      float* __restrict__ scal) {
    __shared__ float rs[256], rm[256];
    const int t = threadIdx.x;
    float ss = 0.f, mx = 0.f;
    for (int i = t; i < 768; i += 256) ss += part[i];
    for (int i = t; i < 2048; i += 256) mx = fmaxf(mx, xmax[i]);
    rs[t] = ss; rm[t] = mx;
    __syncthreads();
    for (int s = 128; s; s >>= 1) {
        if (t < s) { rs[t] += rs[t + s]; rm[t] = fmaxf(rm[t], rm[t + s]); }
        __syncthreads();
    }
    if (t == 0) scal[0] = ALPHA_ * LOG2E_ / (sqrtf(rs[0]) * sqrtf(rm[0]));
}

// ---------------------------------------------------------------------------
// bf16 MFMA flash attention. 4 waves, 64 q/block, KV tile 64, reg-staged
// double-buffer, exp2 domain, defer-max. XCD-contiguous block swizzle.
// ---------------------------------------------------------------------------
__global__ __launch_bounds__(256) void attn_mfma(const unsigned short* __restrict__ Qb,
                                                 const unsigned short* __restrict__ Kb,
                                                 const unsigned short* __restrict__ Vtb,
                                                 const float* __restrict__ KN2,
                                                 const float* __restrict__ scal,
                                                 unsigned short* __restrict__ VALS) {
    __shared__ __align__(16) char lds[24832];
    char* Kt = lds;                  // [64 k][64 d] bf16, swizzled
    char* Vt = lds + 8192;           // [64 d][64 k] bf16, swizzled
    char* Pl = lds + 16384;          // 4 waves x [16 q][64 k] bf16, swizzled
    float* kn2s = (float*)(lds + 24576);

    const int t  = threadIdx.x;
    const int w  = t >> 6;
    const int l  = t & 63;
    const int g  = l >> 4;
    const int c  = l & 15;
    // XCD swizzle: 1024 blocks, 8 XCDs -> 128 contiguous (4 bh) per XCD
    const int bid  = blockIdx.y * gridDim.x + blockIdx.x;
    const int swid = (bid & 7) * 128 + (bid >> 3);
    const int bh = swid >> 5;
    const int qb = swid & 31;
    const float sc    = scal[0];
    const float ts2   = 2.0f * sc;
    const float nscal = -sc;

    const int qrow = qb * 64 + w * 16 + c;
    const size_t qoff = ((size_t)bh * S_ + qrow) * HD_;
    const bf16x8 qf0 = *(const bf16x8*)&Qb[qoff + g * 8];
    const bf16x8 qf1 = *(const bf16x8*)&Qb[qoff + 32 + g * 8];

    f32x4 acc[4];
    #pragma unroll
    for (int dt = 0; dt < 4; ++dt)
        #pragma unroll
        for (int r = 0; r < 4; ++r) acc[dt][r] = 0.f;
    float mrun = -1e30f, lrun = 0.f;

    const size_t kbase  = (size_t)bh * S_ * HD_;
    const size_t vtbase = (size_t)bh * HD_ * S_;
    const float* kn2g = &KN2[(size_t)bh * S_];
    char* Pw = Pl + w * 2048;
    const int swc = (c & 7) << 4;

    const int rr = t >> 3;
    const int jj = (t & 7) * 8;
    const size_t koff0 = kbase + (size_t)rr * HD_ + jj;
    const size_t voff0 = vtbase + (size_t)rr * S_ + jj;
    const int d0 = rr * 128 + ((jj * 2) ^ ((rr & 7) << 4));

    uint4 kA0, kA1, vA0, vA1, kB0, kB1, vB0, vB1;
    float nA, nB;

#define LOADT(K0, K1, V0, V1, NN, off) do {                                   \
        K0 = *(const uint4*)&Kb[koff0 + (size_t)(off) * HD_];                 \
        K1 = *(const uint4*)&Kb[koff0 + (size_t)((off) + 32) * HD_];          \
        V0 = *(const uint4*)&Vtb[voff0 + (off)];                              \
        V1 = *(const uint4*)&Vtb[voff0 + (size_t)32 * S_ + (off)];            \
        NN = (t < 64) ? (nscal * kn2g[(off) + t]) : 0.f;                      \
    } while (0)

#define STORET(K0, K1, V0, V1, NN) do {                                       \
        *(uint4*)(Kt + d0) = K0; *(uint4*)(Kt + d0 + 4096) = K1;              \
        *(uint4*)(Vt + d0) = V0; *(uint4*)(Vt + d0 + 4096) = V1;              \
        if (t < 64) kn2s[t] = NN;                                             \
    } while (0)

    auto compute_tile = [&]() {
        float sl[16];
        #pragma unroll
        for (int kt = 0; kt < 4; ++kt) {
            const int r  = kt * 16 + c;
            const int sw = (r & 7) << 4;
            const bf16x8 ka0 = *(const bf16x8*)(Kt + r * 128 + ((g * 16) ^ sw));
            const bf16x8 ka1 = *(const bf16x8*)(Kt + r * 128 + ((64 + g * 16) ^ sw));
            f32x4 sacc = {0.f, 0.f, 0.f, 0.f};
            sacc = __builtin_amdgcn_mfma_f32_16x16x32_bf16(ka0, qf0, sacc, 0, 0, 0);
            sacc = __builtin_amdgcn_mfma_f32_16x16x32_bf16(ka1, qf1, sacc, 0, 0, 0);
            const f32x4 kn4 = *(const f32x4*)&kn2s[kt * 16 + g * 4];
            #pragma unroll
            for (int rg = 0; rg < 4; ++rg)
                sl[kt * 4 + rg] = fmaf(sacc[rg], ts2, kn4[rg]);
        }
        // max via max3-friendly tree (T17)
        const float a0 = fmaxf(fmaxf(sl[0],  sl[1]),  sl[2]);
        const float a1 = fmaxf(fmaxf(sl[3],  sl[4]),  sl[5]);
        const float a2 = fmaxf(fmaxf(sl[6],  sl[7]),  sl[8]);
        const float a3 = fmaxf(fmaxf(sl[9],  sl[10]), sl[11]);
        const float a4 = fmaxf(fmaxf(sl[12], sl[13]), sl[14]);
        float pmax = fmaxf(fmaxf(fmaxf(a0, a1), a2), fmaxf(fmaxf(a3, a4), sl[15]));
        pmax = fmaxf(pmax, __shfl_xor(pmax, 16));
        pmax = fmaxf(pmax, __shfl_xor(pmax, 32));
        if (!__all(pmax <= mrun + 8.f)) {            // T13: rare rescale
            const float mnew = fmaxf(mrun, pmax);
            const float cf = exp2f(mrun - mnew);
            lrun *= cf;
            #pragma unroll
            for (int dt = 0; dt < 4; ++dt)
                #pragma unroll
                for (int r = 0; r < 4; ++r) acc[dt][r] *= cf;
            mrun = mnew;
        }
        float p[16];
        float psum = 0.f;
        #pragma unroll
        for (int j = 0; j < 16; ++j) { p[j] = exp2f(sl[j] - mrun); psum += p[j]; }
        psum += __shfl_xor(psum, 16);
        psum += __shfl_xor(psum, 32);
        lrun += psum;

        #pragma unroll
        for (int kt = 0; kt < 4; ++kt) {
            uint2 pk;
            pk.x = pack2bf(p[kt * 4 + 0], p[kt * 4 + 1]);
            pk.y = pack2bf(p[kt * 4 + 2], p[kt * 4 + 3]);
            const int cb = kt * 32 + g * 8;
            *(uint2*)(Pw + c * 128 + (cb ^ swc)) = pk;
        }
        asm volatile("s_waitcnt lgkmcnt(0)" ::: "memory");
        __builtin_amdgcn_sched_barrier(0);

        const bf16x8 pa0 = *(const bf16x8*)(Pw + c * 128 + ((g * 16) ^ swc));
        const bf16x8 pa1 = *(const bf16x8*)(Pw + c * 128 + ((64 + g * 16) ^ swc));
        #pragma unroll
        for (int dt = 0; dt < 4; ++dt) {
            const int r  = dt * 16 + c;
            const int sw = (r & 7) << 4;
            const bf16x8 vb0 = *(const bf16x8*)(Vt + r * 128 + ((g * 16) ^ sw));
            const bf16x8 vb1 = *(const bf16x8*)(Vt + r * 128 + ((64 + g * 16) ^ sw));
            acc[dt] = __builtin_amdgcn_mfma_f32_16x16x32_bf16(pa0, vb0, acc[dt], 0, 0, 0);
            acc[dt] = __builtin_amdgcn_mfma_f32_16x16x32_bf16(pa1, vb1, acc[dt], 0, 0, 0);
        }
    };

    LOADT(kA0, kA1, vA0, vA1, nA, 0);
    for (int kt0 = 0; kt0 < S_; kt0 += 128) {
        __syncthreads();
        STORET(kA0, kA1, vA0, vA1, nA);
        __syncthreads();
        LOADT(kB0, kB1, vB0, vB1, nB, kt0 + 64);   // lands during compute
        compute_tile();
        __syncthreads();
        STORET(kB0, kB1, vB0, vB1, nB);
        __syncthreads();
        if (kt0 + 128 < S_) LOADT(kA0, kA1, vA0, vA1, nA, kt0 + 128);
        compute_tile();
    }
#undef LOADT
#undef STORET

    // epilogue -> bf16 VAL [B,S,E]
    const int b = bh >> 3, h = bh & 7;
    #pragma unroll
    for (int reg = 0; reg < 4; ++reg) {
        const float lq  = __shfl(lrun, g * 4 + reg);
        const float inv = 1.0f / lq;
        const int qg = qb * 64 + w * 16 + g * 4 + reg;
        unsigned short* dst = &VALS[((size_t)b * S_ + qg) * E_ + h * HD_];
        #pragma unroll
        for (int dt = 0; dt < 4; ++dt)
            dst[dt * 16 + c] = f2bf(acc[dt][reg] * inv);
    }
}

// ---------------------------------------------------------------------------
extern "C" void kernel_launch(void* const* d_in, const int* in_sizes, int n_in,
                              void* d_out, int out_size, void* d_ws, size_t ws_size,
                              hipStream_t stream) {
    const float* x    = (const float*)d_in[0];
    const float* Wqkv = (const float*)d_in[1];
    const float* bqkv = (const float*)d_in[2];
    const float* Wo   = (const float*)d_in[3];
    const float* bo   = (const float*)d_in[4];
    float* out = (float*)d_out;

    char* ws = (char*)d_ws;
    unsigned short* Qb    = (unsigned short*)(ws);                        // 8 MB
    unsigned short* Kb    = (unsigned short*)(ws + ((size_t) 8 << 20));   // 8 MB
    unsigned short* Vtb   = (unsigned short*)(ws + ((size_t)16 << 20));   // 8 MB
    unsigned short* VALb  = (unsigned short*)(ws + ((size_t)24 << 20));   // 8 MB
    unsigned short* xbf   = (unsigned short*)(ws + ((size_t)32 << 20));   // 8 MB
    unsigned short* Wqkvb = (unsigned short*)(ws + ((size_t)40 << 20));   // 1.5 MB
    unsigned short* Wob   = (unsigned short*)(ws + ((size_t)42 << 20));   // 0.5 MB
    float* KN2  = (float*)(ws + ((size_t)43 << 20));                      // 256 KB
    float* PART = (float*)(ws + ((size_t)43 << 20) + (256 << 10));        // 3 KB
    float* XMAX = (float*)(ws + ((size_t)43 << 20) + (260 << 10));        // 8 KB
    float* SCAL = (float*)(ws + ((size_t)43 << 20) + (272 << 10));

    // 0) x -> bf16 + per-block row-norm max; weights -> bf16 (one kernel)
    prep<<<2560, 256, 0, stream>>>(x, Wqkv, Wo, xbf, Wqkvb, Wob, XMAX);

    // 1) QKV projection (bf16 MFMA) + sum(q^2) partials + per-key ||k||^2
    gemm_mfma<3 * E_, 0><<<dim3(12, 64), 256, 0, stream>>>(xbf, Wqkvb, bqkv, Qb, Kb, Vtb, PART, KN2);

    // 2) normalizer scalar
    finalize_scale<<<1, 256, 0, stream>>>(PART, XMAX, SCAL);

    // 3) MFMA flash attention -> VAL bf16 [B,S,E]
    attn_mfma<<<dim3(32, 32), 256, 0, stream>>>(Qb, Kb, Vtb, KN2, SCAL, VALb);

    // 4) output projection (bf16 MFMA, fp32 out)
    gemm_mfma<E_, 1><<<dim3(4, 64), 256, 0, stream>>>(VALb, Wob, bo, out, nullptr, nullptr, nullptr, nullptr);
}

// Round 10
// 127.040 us; speedup vs baseline: 12.2290x; 1.2761x over previous
//
#include <hip/hip_runtime.h>
#include <hip/hip_bf16.h>
#include <math.h>

#define B_ 4
#define S_ 2048
#define D_ 512
#define E_ 512
#define H_ 8
#define HD_ 64
#define ALPHA_ 1.0f
#define M_ (B_*S_)   // 8192
#define LOG2E_ 1.44269504088896340736f

typedef __attribute__((ext_vector_type(8))) short bf16x8;
typedef __attribute__((ext_vector_type(4))) float f32x4;

__device__ inline unsigned short f2bf(float f) {
    union { __hip_bfloat16 h; unsigned short u; } cv;
    cv.h = __float2bfloat16(f);
    return cv.u;
}
__device__ inline unsigned pack2bf(float a, float b) {
    union { __hip_bfloat162 h; unsigned u; } cv;
    cv.h = __float22bfloat162_rn(make_float2(a, b));
    return cv.u;
}

// ---------------------------------------------------------------------------
// prep: blocks 0..2047: x -> bf16 + per-block max ||x_row||^2 (no atomics)
//       blocks 2048..2559: Wqkv,Wo -> bf16
// ---------------------------------------------------------------------------
__global__ __launch_bounds__(256) void prep(const float* __restrict__ x,
                                            const float* __restrict__ Wqkv,
                                            const float* __restrict__ Wo,
                                            unsigned short* __restrict__ xbf,
                                            unsigned short* __restrict__ Wqkvb,
                                            unsigned short* __restrict__ Wob,
                                            float* __restrict__ xmax) {
    const int t   = threadIdx.x;
    const int bid = blockIdx.x;
    if (bid < 2048) {
        __shared__ float red[4];
        const int wid = t >> 6, lane = t & 63;
        const int row = bid * 4 + wid;
        const float* xr = &x[(size_t)row * D_ + lane * 8];
        const float4 a = *(const float4*)xr;
        const float4 b = *(const float4*)(xr + 4);
        float ss = a.x*a.x + a.y*a.y + a.z*a.z + a.w*a.w
                 + b.x*b.x + b.y*b.y + b.z*b.z + b.w*b.w;
        uint4 o;
        o.x = pack2bf(a.x, a.y); o.y = pack2bf(a.z, a.w);
        o.z = pack2bf(b.x, b.y); o.w = pack2bf(b.z, b.w);
        *(uint4*)&xbf[(size_t)row * D_ + lane * 8] = o;
        #pragma unroll
        for (int off = 32; off; off >>= 1) ss += __shfl_xor(ss, off);
        if (lane == 0) red[wid] = ss;
        __syncthreads();
        if (t == 0)
            xmax[bid] = fmaxf(fmaxf(red[0], red[1]), fmaxf(red[2], red[3]));
    } else {
        const int i  = (bid - 2048) * 256 + t;       // 0..131071
        const int nq = 3 * E_ * D_ / 8;              // 98304
        const float* src; unsigned short* dst; int j;
        if (i < nq) { src = Wqkv; dst = Wqkvb; j = i; }
        else        { src = Wo;   dst = Wob;   j = i - nq; }
        const float4 a = *(const float4*)&src[(size_t)j * 8];
        const float4 b = *(const float4*)&src[(size_t)j * 8 + 4];
        uint4 o;
        o.x = pack2bf(a.x, a.y); o.y = pack2bf(a.z, a.w);
        o.z = pack2bf(b.x, b.y); o.w = pack2bf(b.z, b.w);
        *(uint4*)&dst[(size_t)j * 8] = o;
    }
}

// ---------------------------------------------------------------------------
// bf16 MFMA GEMM: C[M,N] = A[M,512] @ W[N,512]^T + bias[N]
// 128x128 tile, BK=64, 4 waves (2x2). LDS XOR-swizzled (byte ^= (row&7)<<4).
// MODE 0: per-64-col-half class (q/k/v): scatter bf16 Q,K [bh][S][64],
//         V^T [bh][64][S] (8B packed); + sum(q^2) partials; + per-key ||k||^2.
// MODE 1: fp32 C row-major [M][N]
// ---------------------------------------------------------------------------
template<int N, int MODE>
__global__ __launch_bounds__(256) void gemm_mfma(const unsigned short* __restrict__ Abf,
                                                 const unsigned short* __restrict__ Wbf,
                                                 const float* __restrict__ bias,
                                                 void* __restrict__ out0,
                                                 void* __restrict__ out1,
                                                 void* __restrict__ out2,
                                                 float* __restrict__ part,
                                                 float* __restrict__ kn2) {
    __shared__ __align__(16) char At[16384];
    __shared__ __align__(16) char Wt[16384];

    const int t  = threadIdx.x;
    const int w  = t >> 6;
    const int l  = t & 63;
    const int g  = l >> 4;
    const int c  = l & 15;
    const int wm = w >> 1;
    const int wn = w & 1;
    const int m0 = blockIdx.y * 128;
    const int n0 = blockIdx.x * 128;

    f32x4 acc[4][4];
    #pragma unroll
    for (int i = 0; i < 4; ++i)
        #pragma unroll
        for (int j = 0; j < 4; ++j)
            #pragma unroll
            for (int r = 0; r < 4; ++r) acc[i][j][r] = 0.f;

    for (int k0 = 0; k0 < 512; k0 += 64) {
        __syncthreads();
        #pragma unroll
        for (int i = 0; i < 4; ++i) {
            const int idx = t + i * 256;
            const int r   = idx >> 3;
            const int j   = idx & 7;
            const int dst = r * 128 + ((j * 16) ^ ((r & 7) << 4));
            *(uint4*)(At + dst) = *(const uint4*)&Abf[(size_t)(m0 + r) * 512 + k0 + j * 8];
            *(uint4*)(Wt + dst) = *(const uint4*)&Wbf[(size_t)(n0 + r) * 512 + k0 + j * 8];
        }
        __syncthreads();

        bf16x8 af[4][2], wf[4][2];
        #pragma unroll
        for (int mt = 0; mt < 4; ++mt) {
            const int row = wm * 64 + mt * 16 + c;
            const int sw  = (row & 7) << 4;
            #pragma unroll
            for (int kc = 0; kc < 2; ++kc)
                af[mt][kc] = *(const bf16x8*)(At + row * 128 + (((kc * 4 + g) * 16) ^ sw));
        }
        #pragma unroll
        for (int nt = 0; nt < 4; ++nt) {
            const int row = wn * 64 + nt * 16 + c;
            const int sw  = (row & 7) << 4;
            #pragma unroll
            for (int kc = 0; kc < 2; ++kc)
                wf[nt][kc] = *(const bf16x8*)(Wt + row * 128 + (((kc * 4 + g) * 16) ^ sw));
        }
        #pragma unroll
        for (int mt = 0; mt < 4; ++mt)
            #pragma unroll
            for (int nt = 0; nt < 4; ++nt) {
                acc[mt][nt] = __builtin_amdgcn_mfma_f32_16x16x32_bf16(af[mt][0], wf[nt][0], acc[mt][nt], 0, 0, 0);
                acc[mt][nt] = __builtin_amdgcn_mfma_f32_16x16x32_bf16(af[mt][1], wf[nt][1], acc[mt][nt], 0, 0, 0);
            }
    }

    if (MODE == 1) {
        #pragma unroll
        for (int mt = 0; mt < 4; ++mt)
            #pragma unroll
            for (int reg = 0; reg < 4; ++reg) {
                const int m = m0 + wm * 64 + mt * 16 + g * 4 + reg;
                #pragma unroll
                for (int nt = 0; nt < 4; ++nt) {
                    const int n = n0 + wn * 64 + nt * 16 + c;
                    ((float*)out0)[(size_t)m * N + n] = acc[mt][nt][reg] + bias[n];
                }
            }
        return;
    }

    // ---- MODE 0: q/k/v scatter by 64-col half ----
    const int hb  = 2 * blockIdx.x + wn;     // half index 0..23
    const int cls = hb % 3;                  // 0=q, 1=k, 2=v
    const int h   = hb / 3;
    const int b   = m0 >> 11;
    const int s0w = (m0 & 2047) + wm * 64;   // base s of this wave
    const size_t bhS = ((size_t)b * H_ + h) * S_;

    float kp[4][4];
    #pragma unroll
    for (int i = 0; i < 4; ++i)
        #pragma unroll
        for (int j = 0; j < 4; ++j) kp[i][j] = 0.f;

    if (cls == 2) {
        unsigned short* Vt_ = (unsigned short*)out2;
        #pragma unroll
        for (int nt = 0; nt < 4; ++nt) {
            const int n = n0 + wn * 64 + nt * 16 + c;
            const float bv = bias[n];
            const int d = nt * 16 + c;
            unsigned short* dbase = Vt_ + (((size_t)b * H_ + h) * HD_ + d) * S_ + s0w;
            #pragma unroll
            for (int mt = 0; mt < 4; ++mt) {
                uint2 pk;
                pk.x = pack2bf(acc[mt][nt][0] + bv, acc[mt][nt][1] + bv);
                pk.y = pack2bf(acc[mt][nt][2] + bv, acc[mt][nt][3] + bv);
                *(uint2*)&dbase[mt * 16 + g * 4] = pk;
            }
        }
    } else {
        unsigned short* dst0 = (cls == 0) ? (unsigned short*)out0 : (unsigned short*)out1;
        #pragma unroll
        for (int nt = 0; nt < 4; ++nt) {
            const int n = n0 + wn * 64 + nt * 16 + c;
            const float bv = bias[n];
            const int d = nt * 16 + c;
            #pragma unroll
            for (int mt = 0; mt < 4; ++mt)
                #pragma unroll
                for (int reg = 0; reg < 4; ++reg) {
                    const int s = s0w + mt * 16 + g * 4 + reg;
                    const float val = acc[mt][nt][reg] + bv;
                    kp[mt][reg] = fmaf(val, val, kp[mt][reg]);
                    dst0[(bhS + s) * HD_ + d] = f2bf(val);
                }
        }
    }

    __syncthreads();
    if (cls == 1) {
        // per-key ||k||^2: LDS transpose-reduce over the 16 c-lanes
        float* scratch = (float*)At + wm * 1088;       // 64 lanes x 17 floats
        #pragma unroll
        for (int i = 0; i < 16; ++i) scratch[l * 17 + i] = kp[i >> 2][i & 3];
        asm volatile("s_waitcnt lgkmcnt(0)" ::: "memory");
        __builtin_amdgcn_sched_barrier(0);
        float sum = 0.f;
        #pragma unroll
        for (int cc = 0; cc < 16; ++cc)
            sum += scratch[(g * 16 + cc) * 17 + c];
        const int s = s0w + (c >> 2) * 16 + g * 4 + (c & 3);
        kn2[bhS + s] = sum;
    }
    __syncthreads();

    // deterministic per-block sum(q^2) partial (q-class threads hold it in kp)
    float qss = 0.f;
    if (cls == 0) {
        #pragma unroll
        for (int i = 0; i < 4; ++i)
            #pragma unroll
            for (int j = 0; j < 4; ++j) qss += kp[i][j];
    }
    float* red = (float*)At;
    red[t] = qss;
    __syncthreads();
    for (int s = 128; s; s >>= 1) {
        if (t < s) red[t] += red[t + s];
        __syncthreads();
    }
    if (t == 0) part[blockIdx.y * gridDim.x + blockIdx.x] = red[0];
}

// ---------------------------------------------------------------------------
// finalize: scal = ALPHA*log2(e) / (sqrt(sum q^2) * sqrt(max row norm^2))
// ---------------------------------------------------------------------------
__global__ __launch_bounds__(256) void finalize_scale(const float* __restrict__ part,
                                                      const float* __restrict__ xmax,
                                                      float* __restrict__ scal) {
    __shared__ float rs[256], rm[256];
    const int t = threadIdx.x;
    float ss = 0.f, mx = 0.f;
    for (int i = t; i < 768; i += 256) ss += part[i];
    for (int i = t; i < 2048; i += 256) mx = fmaxf(mx, xmax[i]);
    rs[t] = ss; rm[t] = mx;
    __syncthreads();
    for (int s = 128; s; s >>= 1) {
        if (t < s) { rs[t] += rs[t + s]; rm[t] = fmaxf(rm[t], rm[t + s]); }
        __syncthreads();
    }
    if (t == 0) scal[0] = ALPHA_ * LOG2E_ / (sqrtf(rs[0]) * sqrtf(rm[0]));
}

// ---------------------------------------------------------------------------
// bf16 MFMA flash attention. 512 thr = 8 waves, 128 q/block, KV tile 64,
// reg-staged double-buffer, exp2 domain, FIXED m=0 (scores provably tiny:
// s = scale*(2qk-k^2), scale ~ 3e-5 -> no overflow risk; softmax is
// shift-invariant so result identical). Per-lane partial l, reduced once
// at the end. P overlays the K tile (dead after QK^T barrier) for waves
// 0-3, separate 8KB for waves 4-7 -> LDS 24.25KB @ 512 thr.
// ---------------------------------------------------------------------------
__global__ __launch_bounds__(512) void attn_mfma(const unsigned short* __restrict__ Qb,
                                                 const unsigned short* __restrict__ Kb,
                                                 const unsigned short* __restrict__ Vtb,
                                                 const float* __restrict__ KN2,
                                                 const float* __restrict__ scal,
                                                 unsigned short* __restrict__ VALS) {
    __shared__ __align__(16) char lds[24832];
    char* Kt  = lds;                 // [64 k][64 d] bf16, swizzled (P overlay after QK)
    char* Vt  = lds + 8192;          // [64 d][64 k] bf16, swizzled
    char* Pex = lds + 16384;         // waves 4-7 P region
    float* kn2s = (float*)(lds + 24576);

    const int t  = threadIdx.x;
    const int w  = t >> 6;           // 0..7
    const int l  = t & 63;
    const int g  = l >> 4;
    const int c  = l & 15;
    // XCD swizzle: 512 blocks, 8 XCDs -> 64 contiguous (4 bh) per XCD
    const int bid  = blockIdx.y * gridDim.x + blockIdx.x;
    const int swid = (bid & 7) * 64 + (bid >> 3);
    const int bh = swid >> 4;        // 0..31
    const int qb = swid & 15;        // 0..15
    const float sc    = scal[0];
    const float ts2   = 2.0f * sc;
    const float nscal = -sc;

    const int qrow = qb * 128 + w * 16 + c;
    const size_t qoff = ((size_t)bh * S_ + qrow) * HD_;
    const bf16x8 qf0 = *(const bf16x8*)&Qb[qoff + g * 8];
    const bf16x8 qf1 = *(const bf16x8*)&Qb[qoff + 32 + g * 8];

    f32x4 acc[4];
    #pragma unroll
    for (int dt = 0; dt < 4; ++dt)
        #pragma unroll
        for (int r = 0; r < 4; ++r) acc[dt][r] = 0.f;
    float lpart = 0.f;               // per-lane partial sum of p

    const size_t kbase  = (size_t)bh * S_ * HD_;
    const size_t vtbase = (size_t)bh * HD_ * S_;
    const float* kn2g = &KN2[(size_t)bh * S_];
    char* Pw = (w < 4) ? (Kt + w * 2048) : (Pex + (w - 4) * 2048);
    const int swc = (c & 7) << 4;

    // staging: 512 thr, 1 K-uint4 + 1 V-uint4 each. row rr, 16B col jj*2
    const int rr = t >> 3;           // 0..63
    const int jj = (t & 7) * 8;
    const size_t koff0 = kbase + (size_t)rr * HD_ + jj;
    const size_t voff0 = vtbase + (size_t)rr * S_ + jj;
    const int d0 = rr * 128 + ((jj * 2) ^ ((rr & 7) << 4));

    uint4 kA, vA, kB, vB;
    float nA, nB;

#define LOADT(K0, V0, NN, off) do {                                           \
        K0 = *(const uint4*)&Kb[koff0 + (size_t)(off) * HD_];                 \
        V0 = *(const uint4*)&Vtb[voff0 + (off)];                              \
        NN = (t < 64) ? (nscal * kn2g[(off) + t]) : 0.f;                      \
    } while (0)

#define STORET(K0, V0, NN) do {                                               \
        *(uint4*)(Kt + d0) = K0;                                              \
        *(uint4*)(Vt + d0) = V0;                                              \
        if (t < 64) kn2s[t] = NN;                                             \
    } while (0)

    auto compute_tile = [&]() {
        float sl[16];
        #pragma unroll
        for (int kt = 0; kt < 4; ++kt) {
            const int r  = kt * 16 + c;
            const int sw = (r & 7) << 4;
            const bf16x8 ka0 = *(const bf16x8*)(Kt + r * 128 + ((g * 16) ^ sw));
            const bf16x8 ka1 = *(const bf16x8*)(Kt + r * 128 + ((64 + g * 16) ^ sw));
            f32x4 sacc = {0.f, 0.f, 0.f, 0.f};
            sacc = __builtin_amdgcn_mfma_f32_16x16x32_bf16(ka0, qf0, sacc, 0, 0, 0);
            sacc = __builtin_amdgcn_mfma_f32_16x16x32_bf16(ka1, qf1, sacc, 0, 0, 0);
            const f32x4 kn4 = *(const f32x4*)&kn2s[kt * 16 + g * 4];
            #pragma unroll
            for (int rg = 0; rg < 4; ++rg)
                sl[kt * 4 + rg] = fmaf(sacc[rg], ts2, kn4[rg]);
        }
        __syncthreads();             // all waves done reading K -> P may overlay

        float p[16];
        #pragma unroll
        for (int j = 0; j < 16; ++j) { p[j] = exp2f(sl[j]); lpart += p[j]; }

        #pragma unroll
        for (int kt = 0; kt < 4; ++kt) {
            uint2 pk;
            pk.x = pack2bf(p[kt * 4 + 0], p[kt * 4 + 1]);
            pk.y = pack2bf(p[kt * 4 + 2], p[kt * 4 + 3]);
            const int cb = kt * 32 + g * 8;
            *(uint2*)(Pw + c * 128 + (cb ^ swc)) = pk;
        }
        asm volatile("s_waitcnt lgkmcnt(0)" ::: "memory");
        __builtin_amdgcn_sched_barrier(0);

        const bf16x8 pa0 = *(const bf16x8*)(Pw + c * 128 + ((g * 16) ^ swc));
        const bf16x8 pa1 = *(const bf16x8*)(Pw + c * 128 + ((64 + g * 16) ^ swc));
        #pragma unroll
        for (int dt = 0; dt < 4; ++dt) {
            const int r  = dt * 16 + c;
            const int sw = (r & 7) << 4;
            const bf16x8 vb0 = *(const bf16x8*)(Vt + r * 128 + ((g * 16) ^ sw));
            const bf16x8 vb1 = *(const bf16x8*)(Vt + r * 128 + ((64 + g * 16) ^ sw));
            acc[dt] = __builtin_amdgcn_mfma_f32_16x16x32_bf16(pa0, vb0, acc[dt], 0, 0, 0);
            acc[dt] = __builtin_amdgcn_mfma_f32_16x16x32_bf16(pa1, vb1, acc[dt], 0, 0, 0);
        }
    };

    LOADT(kA, vA, nA, 0);
    for (int kt0 = 0; kt0 < S_; kt0 += 128) {
        __syncthreads();             // previous tile's P/V reads complete
        STORET(kA, vA, nA);
        __syncthreads();             // staging visible
        LOADT(kB, vB, nB, kt0 + 64); // issue-early, lands during compute
        compute_tile();
        __syncthreads();
        STORET(kB, vB, nB);
        __syncthreads();
        if (kt0 + 128 < S_) LOADT(kA, vA, nA, kt0 + 128);
        compute_tile();
    }
#undef LOADT
#undef STORET

    // reduce per-lane l partials across the 4 g-groups (once, not per tile)
    lpart += __shfl_xor(lpart, 16);
    lpart += __shfl_xor(lpart, 32);

    // epilogue -> bf16 VAL [B,S,E]
    const int b = bh >> 3, h = bh & 7;
    #pragma unroll
    for (int reg = 0; reg < 4; ++reg) {
        const float lq  = __shfl(lpart, g * 4 + reg);
        const float inv = 1.0f / lq;
        const int qg = qb * 128 + w * 16 + g * 4 + reg;
        unsigned short* dst = &VALS[((size_t)b * S_ + qg) * E_ + h * HD_];
        #pragma unroll
        for (int dt = 0; dt < 4; ++dt)
            dst[dt * 16 + c] = f2bf(acc[dt][reg] * inv);
    }
}

// ---------------------------------------------------------------------------
extern "C" void kernel_launch(void* const* d_in, const int* in_sizes, int n_in,
                              void* d_out, int out_size, void* d_ws, size_t ws_size,
                              hipStream_t stream) {
    const float* x    = (const float*)d_in[0];
    const float* Wqkv = (const float*)d_in[1];
    const float* bqkv = (const float*)d_in[2];
    const float* Wo   = (const float*)d_in[3];
    const float* bo   = (const float*)d_in[4];
    float* out = (float*)d_out;

    char* ws = (char*)d_ws;
    unsigned short* Qb    = (unsigned short*)(ws);                        // 8 MB
    unsigned short* Kb    = (unsigned short*)(ws + ((size_t) 8 << 20));   // 8 MB
    unsigned short* Vtb   = (unsigned short*)(ws + ((size_t)16 << 20));   // 8 MB
    unsigned short* VALb  = (unsigned short*)(ws + ((size_t)24 << 20));   // 8 MB
    unsigned short* xbf   = (unsigned short*)(ws + ((size_t)32 << 20));   // 8 MB
    unsigned short* Wqkvb = (unsigned short*)(ws + ((size_t)40 << 20));   // 1.5 MB
    unsigned short* Wob   = (unsigned short*)(ws + ((size_t)42 << 20));   // 0.5 MB
    float* KN2  = (float*)(ws + ((size_t)43 << 20));                      // 256 KB
    float* PART = (float*)(ws + ((size_t)43 << 20) + (256 << 10));        // 3 KB
    float* XMAX = (float*)(ws + ((size_t)43 << 20) + (260 << 10));        // 8 KB
    float* SCAL = (float*)(ws + ((size_t)43 << 20) + (272 << 10));

    // 0) x -> bf16 + per-block row-norm max; weights -> bf16 (one kernel)
    prep<<<2560, 256, 0, stream>>>(x, Wqkv, Wo, xbf, Wqkvb, Wob, XMAX);

    // 1) QKV projection (bf16 MFMA) + sum(q^2) partials + per-key ||k||^2
    gemm_mfma<3 * E_, 0><<<dim3(12, 64), 256, 0, stream>>>(xbf, Wqkvb, bqkv, Qb, Kb, Vtb, PART, KN2);

    // 2) normalizer scalar
    finalize_scale<<<1, 256, 0, stream>>>(PART, XMAX, SCAL);

    // 3) MFMA flash attention -> VAL bf16 [B,S,E]
    attn_mfma<<<dim3(16, 32), 512, 0, stream>>>(Qb, Kb, Vtb, KN2, SCAL, VALb);

    // 4) output projection (bf16 MFMA, fp32 out)
    gemm_mfma<E_, 1><<<dim3(4, 64), 256, 0, stream>>>(VALb, Wob, bo, out, nullptr, nullptr, nullptr, nullptr);
}